// Round 1
// baseline (2335.466 us; speedup 1.0000x reference)
//
#include <hip/hip_runtime.h>
#include <math.h>

#define N_NODES 40000
#define N_EDGES 640000
#define IN_DIM 128
#define EDGE_DIM 64
#define HID 128

__device__ __forceinline__ void fma4(float4& a, float s, const float4 w) {
    a.x = fmaf(s, w.x, a.x);
    a.y = fmaf(s, w.y, a.y);
    a.z = fmaf(s, w.z, a.z);
    a.w = fmaf(s, w.w, a.w);
}

// ---------------------------------------------------------------------------
// K1: h = node_features @ W_node + b_node        [40000,128] = [40000,128]@[128,128]
// 16 nodes per 256-thread block; thread = (col, node-group), 8 nodes each.
// ---------------------------------------------------------------------------
__global__ __launch_bounds__(256) void k_node_gemm(
    const float* __restrict__ X, const float* __restrict__ W,
    const float* __restrict__ b, float* __restrict__ H)
{
    __shared__ float xs[16 * 128];
    const int tid = threadIdx.x;
    const int base = blockIdx.x * 16;

    const float4* Xg = reinterpret_cast<const float4*>(X + (size_t)base * 128);
    float4* xs4 = reinterpret_cast<float4*>(xs);
#pragma unroll
    for (int i = 0; i < 2; ++i) xs4[tid + 256 * i] = Xg[tid + 256 * i];
    __syncthreads();

    const int col = tid & 127, g = tid >> 7;
    float acc[8];
#pragma unroll
    for (int i = 0; i < 8; ++i) acc[i] = 0.f;

    for (int k = 0; k < 128; ++k) {
        const float w = W[k * 128 + col];
#pragma unroll
        for (int i = 0; i < 8; ++i) acc[i] = fmaf(xs[(g + 2 * i) * 128 + k], w, acc[i]);
    }
    const float bb = b[col];
#pragma unroll
    for (int i = 0; i < 8; ++i) H[(size_t)(base + g + 2 * i) * 128 + col] = acc[i] + bb;
}

// ---------------------------------------------------------------------------
// K2: fused per-edge attention logits.
// 64 edges / 256-thread block. thread = (tc: 4 cols, te: 8 edges).
// z = [h_src | h_dst | he] @ W_att1 + b_att1 ; a = tanh(z)@W_att2 + b_att2
// p = exp(a); denom[src] += p (atomic).
// ---------------------------------------------------------------------------
__device__ __forceinline__ void accum_chunk(
    const float* __restrict__ Wp,   // chunk of W_att1: rows k -> Wp[k*128 + col]
    const float* buf,               // LDS [64][128]
    int te, int tc, float4 acc[8])
{
    const float4* W4 = reinterpret_cast<const float4*>(Wp);
    for (int k4 = 0; k4 < 32; ++k4) {
        const float4 w0 = W4[(k4 * 4 + 0) * 32 + tc];
        const float4 w1 = W4[(k4 * 4 + 1) * 32 + tc];
        const float4 w2 = W4[(k4 * 4 + 2) * 32 + tc];
        const float4 w3 = W4[(k4 * 4 + 3) * 32 + tc];
#pragma unroll
        for (int i = 0; i < 8; ++i) {
            const float4 c = *reinterpret_cast<const float4*>(buf + (te * 8 + i) * 128 + k4 * 4);
            fma4(acc[i], c.x, w0);
            fma4(acc[i], c.y, w1);
            fma4(acc[i], c.z, w2);
            fma4(acc[i], c.w, w3);
        }
    }
}

__global__ __launch_bounds__(256) void k_edge_att(
    const int* __restrict__ srcI, const int* __restrict__ dstI,
    const float* __restrict__ EF, const float* __restrict__ H,
    const float* __restrict__ W_edge, const float* __restrict__ b_edge,
    const float* __restrict__ W1, const float* __restrict__ b1,
    const float* __restrict__ W2, const float* __restrict__ b2,
    float* __restrict__ att_exp, float* __restrict__ denom)
{
    __shared__ float g_buf[64 * 128];   // 32 KB: gathered h rows
    __shared__ float he_buf[64 * 128];  // 32 KB: edge transform
    __shared__ int src_l[64], dst_l[64];

    const int tid = threadIdx.x;
    const int ebase = blockIdx.x * 64;

    if (tid < 64)        src_l[tid] = srcI[ebase + tid];
    else if (tid < 128)  dst_l[tid - 64] = dstI[ebase + tid - 64];
    __syncthreads();

    const int tc = tid & 31, te = tid >> 5;

    // stage h_src rows into g_buf (coalesced float4 gather)
    {
        float4* gb4 = reinterpret_cast<float4*>(g_buf);
        const float4* H4 = reinterpret_cast<const float4*>(H);
#pragma unroll
        for (int i = 0; i < 8; ++i) {
            const int f = tid + 256 * i;
            const int r = f >> 5, c = f & 31;
            gb4[r * 32 + c] = H4[(size_t)src_l[r] * 32 + c];
        }
    }

    // he = EF @ W_edge + b_edge   -> he_buf  (EF read straight from global/L1)
    {
        float4 acc[8];
        const float4 be = reinterpret_cast<const float4*>(b_edge)[tc];
#pragma unroll
        for (int i = 0; i < 8; ++i) acc[i] = be;
        const float4* W4 = reinterpret_cast<const float4*>(W_edge);
        const float4* EF4 = reinterpret_cast<const float4*>(EF);
        for (int k4 = 0; k4 < 16; ++k4) {
            const float4 w0 = W4[(k4 * 4 + 0) * 32 + tc];
            const float4 w1 = W4[(k4 * 4 + 1) * 32 + tc];
            const float4 w2 = W4[(k4 * 4 + 2) * 32 + tc];
            const float4 w3 = W4[(k4 * 4 + 3) * 32 + tc];
#pragma unroll
            for (int i = 0; i < 8; ++i) {
                const int row = te * 8 + i;
                const float4 c4 = EF4[(size_t)(ebase + row) * 16 + k4];
                fma4(acc[i], c4.x, w0);
                fma4(acc[i], c4.y, w1);
                fma4(acc[i], c4.z, w2);
                fma4(acc[i], c4.w, w3);
            }
        }
#pragma unroll
        for (int i = 0; i < 8; ++i)
            reinterpret_cast<float4*>(he_buf)[(te * 8 + i) * 32 + tc] = acc[i];
    }
    __syncthreads();

    float4 accz[8];
    const float4 bb1 = reinterpret_cast<const float4*>(b1)[tc];
#pragma unroll
    for (int i = 0; i < 8; ++i) accz[i] = bb1;

    accum_chunk(W1, g_buf, te, tc, accz);                 // h_src rows 0..127
    __syncthreads();

    // re-stage with h_dst
    {
        float4* gb4 = reinterpret_cast<float4*>(g_buf);
        const float4* H4 = reinterpret_cast<const float4*>(H);
#pragma unroll
        for (int i = 0; i < 8; ++i) {
            const int f = tid + 256 * i;
            const int r = f >> 5, c = f & 31;
            gb4[r * 32 + c] = H4[(size_t)dst_l[r] * 32 + c];
        }
    }
    __syncthreads();

    accum_chunk(W1 + 128 * 128, g_buf, te, tc, accz);     // h_dst rows 128..255
    accum_chunk(W1 + 256 * 128, he_buf, te, tc, accz);    // he    rows 256..383

    // epilogue: a = tanh(z) @ W_att2 + b_att2 ; p = exp(a)
    const float4 w2v = reinterpret_cast<const float4*>(W2)[tc];
    float s[8];
#pragma unroll
    for (int i = 0; i < 8; ++i) {
        const float4 z = accz[i];
        s[i] = tanhf(z.x) * w2v.x + tanhf(z.y) * w2v.y +
               tanhf(z.z) * w2v.z + tanhf(z.w) * w2v.w;
    }
#pragma unroll
    for (int m = 1; m <= 16; m <<= 1) {
#pragma unroll
        for (int i = 0; i < 8; ++i) s[i] += __shfl_xor(s[i], m, 64);
    }
    if (tc < 8) {
        const int el = te * 8 + tc;
        const float p = expf(s[tc] + b2[0]);
        att_exp[ebase + el] = p;
        atomicAdd(&denom[src_l[el]], p);
    }
}

// ---------------------------------------------------------------------------
// K3: agg[src] += h[dst] * (att_exp[e] / denom[src])   (atomic scatter)
// 8 edges / 256-thread block; thread = (edge, 4 cols).
// ---------------------------------------------------------------------------
__global__ __launch_bounds__(256) void k_scatter(
    const int* __restrict__ srcI, const int* __restrict__ dstI,
    const float* __restrict__ H, const float* __restrict__ att_exp,
    const float* __restrict__ denom, float* __restrict__ agg)
{
    const int tid = threadIdx.x;
    const int tc = tid & 31, el = tid >> 5;
    const int e = blockIdx.x * 8 + el;
    const int s = srcI[e], d = dstI[e];
    const float coeff = att_exp[e] / denom[s];
    const float4 hv = reinterpret_cast<const float4*>(H)[(size_t)d * 32 + tc];
    float* ap = agg + (size_t)s * 128 + tc * 4;
    atomicAdd(ap + 0, hv.x * coeff);
    atomicAdd(ap + 1, hv.y * coeff);
    atomicAdd(ap + 2, hv.z * coeff);
    atomicAdd(ap + 3, hv.w * coeff);
}

// ---------------------------------------------------------------------------
// K4: o = agg @ W_out + b_out ; LayerNorm(gamma,beta) ; ReLU
// 4 nodes / 512-thread block; thread = one output element.
// ---------------------------------------------------------------------------
__global__ __launch_bounds__(512) void k_out_ln(
    const float* __restrict__ AGG, const float* __restrict__ W,
    const float* __restrict__ b, const float* __restrict__ gamma,
    const float* __restrict__ beta, float* __restrict__ OUT)
{
    __shared__ float xs[4 * 128];
    __shared__ float red[8][2];
    const int tid = threadIdx.x;
    const int col = tid & 127, g = tid >> 7;
    const int node = blockIdx.x * 4 + g;

    xs[tid] = AGG[(size_t)node * 128 + col];
    __syncthreads();

    float acc = b[col];
    for (int k = 0; k < 128; ++k)
        acc = fmaf(xs[g * 128 + k], W[k * 128 + col], acc);

    float s1 = acc, s2 = acc * acc;
#pragma unroll
    for (int m = 1; m < 64; m <<= 1) {
        s1 += __shfl_xor(s1, m, 64);
        s2 += __shfl_xor(s2, m, 64);
    }
    const int wid = tid >> 6;
    if ((tid & 63) == 0) { red[wid][0] = s1; red[wid][1] = s2; }
    __syncthreads();

    const float S1 = red[2 * g][0] + red[2 * g + 1][0];
    const float S2 = red[2 * g][1] + red[2 * g + 1][1];
    const float mu = S1 * (1.f / 128.f);
    const float var = S2 * (1.f / 128.f) - mu * mu;
    const float r = rsqrtf(var + 1e-5f);
    const float o = (acc - mu) * r * gamma[col] + beta[col];
    OUT[(size_t)node * 128 + col] = o > 0.f ? o : 0.f;
}

// ---------------------------------------------------------------------------
extern "C" void kernel_launch(void* const* d_in, const int* in_sizes, int n_in,
                              void* d_out, int out_size, void* d_ws, size_t ws_size,
                              hipStream_t stream)
{
    const float* node_features = (const float*)d_in[0];
    const int*   edge_index    = (const int*)d_in[1];
    const float* edge_features = (const float*)d_in[2];
    const float* W_node  = (const float*)d_in[3];
    const float* b_node  = (const float*)d_in[4];
    const float* W_edge  = (const float*)d_in[5];
    const float* b_edge  = (const float*)d_in[6];
    const float* W_att1  = (const float*)d_in[7];
    const float* b_att1  = (const float*)d_in[8];
    const float* W_att2  = (const float*)d_in[9];
    const float* b_att2  = (const float*)d_in[10];
    const float* W_out   = (const float*)d_in[11];
    const float* b_out   = (const float*)d_in[12];
    const float* ln_gamma = (const float*)d_in[13];
    const float* ln_beta  = (const float*)d_in[14];
    float* out = (float*)d_out;

    // workspace layout (fp32):
    float* h       = (float*)d_ws;                       // N*H
    float* att_exp = h + (size_t)N_NODES * HID;          // E
    float* denom   = att_exp + N_EDGES;                  // N
    float* agg     = denom + N_NODES;                    // N*H   (contiguous after denom)

    const int* srcI = edge_index;
    const int* dstI = edge_index + N_EDGES;

    // zero the accumulators (denom + agg are contiguous)
    hipMemsetAsync(denom, 0, sizeof(float) * ((size_t)N_NODES + (size_t)N_NODES * HID), stream);

    k_node_gemm<<<N_NODES / 16, 256, 0, stream>>>(node_features, W_node, b_node, h);
    k_edge_att<<<N_EDGES / 64, 256, 0, stream>>>(srcI, dstI, edge_features, h,
                                                 W_edge, b_edge, W_att1, b_att1,
                                                 W_att2, b_att2, att_exp, denom);
    k_scatter<<<N_EDGES / 8, 256, 0, stream>>>(srcI, dstI, h, att_exp, denom, agg);
    k_out_ln<<<N_NODES / 4, 512, 0, stream>>>(agg, W_out, b_out, ln_gamma, ln_beta, out);
}

// Round 2
// 1382.966 us; speedup vs baseline: 1.6887x; 1.6887x over previous
//
#include <hip/hip_runtime.h>
#include <math.h>

#define N_NODES 40000
#define N_EDGES 640000
#define IN_DIM 128
#define EDGE_DIM 64
#define HID 128

typedef __attribute__((ext_vector_type(8))) short bf16x8;
typedef __attribute__((ext_vector_type(4))) float f32x4;

__device__ __forceinline__ ushort f2bf(float f) {
    unsigned int x = __float_as_uint(f);
    x += 0x7fffu + ((x >> 16) & 1u);
    return (ushort)(x >> 16);
}

// ---------------------------------------------------------------------------
// K1: h = node_features @ W_node + b_node ; writes fp32 h AND bf16 copy.
// ---------------------------------------------------------------------------
__global__ __launch_bounds__(256) void k_node_gemm(
    const float* __restrict__ X, const float* __restrict__ W,
    const float* __restrict__ b, float* __restrict__ H,
    ushort* __restrict__ Hb)
{
    __shared__ float xs[16 * 128];
    const int tid = threadIdx.x;
    const int base = blockIdx.x * 16;

    const float4* Xg = reinterpret_cast<const float4*>(X + (size_t)base * 128);
    float4* xs4 = reinterpret_cast<float4*>(xs);
#pragma unroll
    for (int i = 0; i < 2; ++i) xs4[tid + 256 * i] = Xg[tid + 256 * i];
    __syncthreads();

    const int col = tid & 127, g = tid >> 7;
    float acc[8];
#pragma unroll
    for (int i = 0; i < 8; ++i) acc[i] = 0.f;

    for (int k = 0; k < 128; ++k) {
        const float w = W[k * 128 + col];
#pragma unroll
        for (int i = 0; i < 8; ++i) acc[i] = fmaf(xs[(g + 2 * i) * 128 + k], w, acc[i]);
    }
    const float bb = b[col];
#pragma unroll
    for (int i = 0; i < 8; ++i) {
        const float v = acc[i] + bb;
        const size_t off = (size_t)(base + g + 2 * i) * 128 + col;
        H[off] = v;
        Hb[off] = f2bf(v);
    }
}

// ---------------------------------------------------------------------------
// Setup A: W_comb = W_edge @ W1[256:384]  (64x128); b_eff = b_att1 + b_edge@W1he
// ---------------------------------------------------------------------------
__global__ __launch_bounds__(256) void k_wcomb(
    const float* __restrict__ W_edge, const float* __restrict__ W1,
    const float* __restrict__ b_att1, const float* __restrict__ b_edge,
    float* __restrict__ Wc, float* __restrict__ b_eff)
{
    const float* W1he = W1 + 256 * 128;
    if (blockIdx.x == 32) {
        const int n = threadIdx.x;
        if (n < 128) {
            float s = b_att1[n];
            for (int k = 0; k < 128; ++k) s = fmaf(b_edge[k], W1he[k * 128 + n], s);
            b_eff[n] = s;
        }
        return;
    }
    const int idx = blockIdx.x * 256 + threadIdx.x;   // 0..8191
    const int row = idx >> 7, n = idx & 127;
    float s = 0.f;
    for (int k = 0; k < 128; ++k) s = fmaf(W_edge[row * 128 + k], W1he[k * 128 + n], s);
    Wc[idx] = s;
}

// ---------------------------------------------------------------------------
// Setup B: pack B-operand fragments in MFMA lane order, bf16.
// pack[k0][nt][lane][j]; global k = k0*32 + (lane>>4)*8 + j ; n = nt*16 + (lane&15)
// k<256 -> W1[k][n] ; k>=256 -> W_comb[k-256][n]
// ---------------------------------------------------------------------------
__global__ __launch_bounds__(256) void k_pack(
    const float* __restrict__ W1, const float* __restrict__ Wc,
    ushort* __restrict__ pack)
{
    const int idx = blockIdx.x * 256 + threadIdx.x;   // 0..40959
    const int j = idx & 7, lane = (idx >> 3) & 63, nt = (idx >> 9) & 7, k0 = idx >> 12;
    const int k = k0 * 32 + (lane >> 4) * 8 + j;
    const int n = nt * 16 + (lane & 15);
    const float v = (k < 256) ? W1[k * 128 + n] : Wc[(k - 256) * 128 + n];
    pack[idx] = f2bf(v);
}

// ---------------------------------------------------------------------------
// K2: per-edge attention logits via MFMA.
// 64 edges/block, 4 waves; wave w owns 16 edges (m-tile), all 8 n-tiles, K=320.
// z = [h_src | h_dst | EF] @ Bpack + b_eff ; a = tanh(z)@W2 + b2 ; p = exp(a)
// ---------------------------------------------------------------------------
__global__ __launch_bounds__(256) void k_edge_att_mfma(
    const int* __restrict__ srcI, const int* __restrict__ dstI,
    const float* __restrict__ EF, const ushort* __restrict__ Hb,
    const ushort* __restrict__ Bpack, const float* __restrict__ b_eff,
    const float* __restrict__ W2, const float* __restrict__ b2,
    float* __restrict__ att_exp, float* __restrict__ denom)
{
    const int tid = threadIdx.x;
    const int wave = tid >> 6, lane = tid & 63;
    const int r = lane & 15, g = lane >> 4;
    const int ebase = blockIdx.x * 64 + wave * 16;
    const int e = ebase + r;

    const int s_idx = srcI[e], d_idx = dstI[e];
    const ushort* rowS = Hb + (size_t)s_idx * 128 + g * 8;
    const ushort* rowD = Hb + (size_t)d_idx * 128 + g * 8;
    const float*  rowE = EF + (size_t)e * 64 + g * 8;
    const bf16x8* Bp = reinterpret_cast<const bf16x8*>(Bpack);

    f32x4 acc[8];
#pragma unroll
    for (int nt = 0; nt < 8; ++nt) {
        const float bv = b_eff[nt * 16 + r];
        acc[nt] = (f32x4){bv, bv, bv, bv};
    }

    // chunk 1: h_src (k0 = 0..3)
#pragma unroll
    for (int k0 = 0; k0 < 4; ++k0) {
        const bf16x8 a = *reinterpret_cast<const bf16x8*>(rowS + k0 * 32);
#pragma unroll
        for (int nt = 0; nt < 8; ++nt)
            acc[nt] = __builtin_amdgcn_mfma_f32_16x16x32_bf16(
                a, Bp[(k0 * 8 + nt) * 64 + lane], acc[nt], 0, 0, 0);
    }
    // chunk 2: h_dst (k0 = 4..7)
#pragma unroll
    for (int k0 = 0; k0 < 4; ++k0) {
        const bf16x8 a = *reinterpret_cast<const bf16x8*>(rowD + k0 * 32);
#pragma unroll
        for (int nt = 0; nt < 8; ++nt)
            acc[nt] = __builtin_amdgcn_mfma_f32_16x16x32_bf16(
                a, Bp[((k0 + 4) * 8 + nt) * 64 + lane], acc[nt], 0, 0, 0);
    }
    // chunk 3: EF fp32 -> bf16 on the fly (k0 = 8..9)
#pragma unroll
    for (int k0 = 0; k0 < 2; ++k0) {
        const float4 e0 = *reinterpret_cast<const float4*>(rowE + k0 * 32);
        const float4 e1 = *reinterpret_cast<const float4*>(rowE + k0 * 32 + 4);
        bf16x8 a;
        a[0] = (short)f2bf(e0.x); a[1] = (short)f2bf(e0.y);
        a[2] = (short)f2bf(e0.z); a[3] = (short)f2bf(e0.w);
        a[4] = (short)f2bf(e1.x); a[5] = (short)f2bf(e1.y);
        a[6] = (short)f2bf(e1.z); a[7] = (short)f2bf(e1.w);
#pragma unroll
        for (int nt = 0; nt < 8; ++nt)
            acc[nt] = __builtin_amdgcn_mfma_f32_16x16x32_bf16(
                a, Bp[((k0 + 8) * 8 + nt) * 64 + lane], acc[nt], 0, 0, 0);
    }

    // epilogue: per-lane rows = g*4+q, col = nt*16+r
    float part[4] = {0.f, 0.f, 0.f, 0.f};
#pragma unroll
    for (int nt = 0; nt < 8; ++nt) {
        const float w2v = W2[nt * 16 + r];
#pragma unroll
        for (int q = 0; q < 4; ++q)
            part[q] = fmaf(tanhf(acc[nt][q]), w2v, part[q]);
    }
#pragma unroll
    for (int m = 1; m <= 8; m <<= 1) {
#pragma unroll
        for (int q = 0; q < 4; ++q) part[q] += __shfl_xor(part[q], m, 64);
    }
    if (r == 0) {
        const float bb2 = b2[0];
#pragma unroll
        for (int q = 0; q < 4; ++q) {
            const int eo = ebase + g * 4 + q;
            const float p = expf(part[q] + bb2);
            att_exp[eo] = p;
            atomicAdd(&denom[srcI[eo]], p);
        }
    }
}

// ---------------------------------------------------------------------------
// K3: agg[src] += h[dst] * (att_exp[e] / denom[src])   (atomic scatter)
// ---------------------------------------------------------------------------
__global__ __launch_bounds__(256) void k_scatter(
    const int* __restrict__ srcI, const int* __restrict__ dstI,
    const float* __restrict__ H, const float* __restrict__ att_exp,
    const float* __restrict__ denom, float* __restrict__ agg)
{
    const int tid = threadIdx.x;
    const int tc = tid & 31, el = tid >> 5;
    const int e = blockIdx.x * 8 + el;
    const int s = srcI[e], d = dstI[e];
    const float coeff = att_exp[e] / denom[s];
    const float4 hv = reinterpret_cast<const float4*>(H)[(size_t)d * 32 + tc];
    float* ap = agg + (size_t)s * 128 + tc * 4;
    atomicAdd(ap + 0, hv.x * coeff);
    atomicAdd(ap + 1, hv.y * coeff);
    atomicAdd(ap + 2, hv.z * coeff);
    atomicAdd(ap + 3, hv.w * coeff);
}

// ---------------------------------------------------------------------------
// K4: o = agg @ W_out + b_out ; LayerNorm ; ReLU
// ---------------------------------------------------------------------------
__global__ __launch_bounds__(512) void k_out_ln(
    const float* __restrict__ AGG, const float* __restrict__ W,
    const float* __restrict__ b, const float* __restrict__ gamma,
    const float* __restrict__ beta, float* __restrict__ OUT)
{
    __shared__ float xs[4 * 128];
    __shared__ float red[8][2];
    const int tid = threadIdx.x;
    const int col = tid & 127, g = tid >> 7;
    const int node = blockIdx.x * 4 + g;

    xs[tid] = AGG[(size_t)node * 128 + col];
    __syncthreads();

    float acc = b[col];
    for (int k = 0; k < 128; ++k)
        acc = fmaf(xs[g * 128 + k], W[k * 128 + col], acc);

    float s1 = acc, s2 = acc * acc;
#pragma unroll
    for (int m = 1; m < 64; m <<= 1) {
        s1 += __shfl_xor(s1, m, 64);
        s2 += __shfl_xor(s2, m, 64);
    }
    const int wid = tid >> 6;
    if ((tid & 63) == 0) { red[wid][0] = s1; red[wid][1] = s2; }
    __syncthreads();

    const float S1 = red[2 * g][0] + red[2 * g + 1][0];
    const float S2 = red[2 * g][1] + red[2 * g + 1][1];
    const float mu = S1 * (1.f / 128.f);
    const float var = S2 * (1.f / 128.f) - mu * mu;
    const float rr = rsqrtf(var + 1e-5f);
    const float o = (acc - mu) * rr * gamma[col] + beta[col];
    OUT[(size_t)node * 128 + col] = o > 0.f ? o : 0.f;
}

// ---------------------------------------------------------------------------
extern "C" void kernel_launch(void* const* d_in, const int* in_sizes, int n_in,
                              void* d_out, int out_size, void* d_ws, size_t ws_size,
                              hipStream_t stream)
{
    const float* node_features = (const float*)d_in[0];
    const int*   edge_index    = (const int*)d_in[1];
    const float* edge_features = (const float*)d_in[2];
    const float* W_node  = (const float*)d_in[3];
    const float* b_node  = (const float*)d_in[4];
    const float* W_edge  = (const float*)d_in[5];
    const float* b_edge  = (const float*)d_in[6];
    const float* W_att1  = (const float*)d_in[7];
    const float* b_att1  = (const float*)d_in[8];
    const float* W_att2  = (const float*)d_in[9];
    const float* b_att2  = (const float*)d_in[10];
    const float* W_out   = (const float*)d_in[11];
    const float* b_out   = (const float*)d_in[12];
    const float* ln_gamma = (const float*)d_in[13];
    const float* ln_beta  = (const float*)d_in[14];
    float* out = (float*)d_out;

    // workspace layout (byte offsets, all 16B-aligned)
    char* ws = (char*)d_ws;
    float*  h       = (float*)(ws);                       // N*H fp32      20,480,000 B
    ushort* hb      = (ushort*)(ws + 20480000);           // N*H bf16      10,240,000 B
    float*  att_exp = (float*)(ws + 30720000);            // E fp32         2,560,000 B
    float*  denom   = (float*)(ws + 33280000);            // N fp32           160,000 B
    float*  agg     = (float*)(ws + 33440000);            // N*H fp32      20,480,000 B
    float*  Wc      = (float*)(ws + 53920000);            // 64*128 fp32       32,768 B
    float*  b_eff   = (float*)(ws + 53952768);            // 128 fp32             512 B
    ushort* pack    = (ushort*)(ws + 53953280);           // 40960 bf16        81,920 B

    const int* srcI = edge_index;
    const int* dstI = edge_index + N_EDGES;

    // zero accumulators (denom + agg are contiguous)
    hipMemsetAsync(denom, 0, sizeof(float) * ((size_t)N_NODES + (size_t)N_NODES * HID), stream);

    k_node_gemm<<<N_NODES / 16, 256, 0, stream>>>(node_features, W_node, b_node, h, hb);
    k_wcomb<<<33, 256, 0, stream>>>(W_edge, W_att1, b_att1, b_edge, Wc, b_eff);
    k_pack<<<160, 256, 0, stream>>>(W_att1, Wc, pack);
    k_edge_att_mfma<<<N_EDGES / 64, 256, 0, stream>>>(srcI, dstI, edge_features, hb,
                                                      pack, b_eff, W_att2, b_att2,
                                                      att_exp, denom);
    k_scatter<<<N_EDGES / 8, 256, 0, stream>>>(srcI, dstI, h, att_exp, denom, agg);
    k_out_ln<<<N_NODES / 4, 512, 0, stream>>>(agg, W_out, b_out, ln_gamma, ln_beta, out);
}

// Round 7
// 447.442 us; speedup vs baseline: 5.2196x; 3.0908x over previous
//
#include <hip/hip_runtime.h>
#include <math.h>

#define N_NODES 40000
#define N_EDGES 640000
#define IN_DIM 128
#define EDGE_DIM 64
#define HID 128

typedef __attribute__((ext_vector_type(8))) short bf16x8;
typedef __attribute__((ext_vector_type(4))) float f32x4;

__device__ __forceinline__ ushort f2bf(float f) {
    unsigned int x = __float_as_uint(f);
    x += 0x7fffu + ((x >> 16) & 1u);
    return (ushort)(x >> 16);
}
__device__ __forceinline__ float bf2f(ushort u) {
    return __uint_as_float(((unsigned int)u) << 16);
}

// ---------------------------------------------------------------------------
// K1: h = node_features @ W_node + b_node ; bf16 output only.
// ---------------------------------------------------------------------------
__global__ __launch_bounds__(256) void k_node_gemm(
    const float* __restrict__ X, const float* __restrict__ W,
    const float* __restrict__ b, ushort* __restrict__ Hb)
{
    __shared__ float xs[16 * 128];
    const int tid = threadIdx.x;
    const int base = blockIdx.x * 16;

    const float4* Xg = reinterpret_cast<const float4*>(X + (size_t)base * 128);
    float4* xs4 = reinterpret_cast<float4*>(xs);
#pragma unroll
    for (int i = 0; i < 2; ++i) xs4[tid + 256 * i] = Xg[tid + 256 * i];
    __syncthreads();

    const int col = tid & 127, g = tid >> 7;
    float acc[8];
#pragma unroll
    for (int i = 0; i < 8; ++i) acc[i] = 0.f;

    for (int k = 0; k < 128; ++k) {
        const float w = W[k * 128 + col];
#pragma unroll
        for (int i = 0; i < 8; ++i) acc[i] = fmaf(xs[(g + 2 * i) * 128 + k], w, acc[i]);
    }
    const float bb = b[col];
#pragma unroll
    for (int i = 0; i < 8; ++i)
        Hb[(size_t)(base + g + 2 * i) * 128 + col] = f2bf(acc[i] + bb);
}

// ---------------------------------------------------------------------------
// Setup A: W_comb = W_edge @ W1[256:384]; b_eff = b_att1 + b_edge @ W1he
// ---------------------------------------------------------------------------
__global__ __launch_bounds__(256) void k_wcomb(
    const float* __restrict__ W_edge, const float* __restrict__ W1,
    const float* __restrict__ b_att1, const float* __restrict__ b_edge,
    float* __restrict__ Wc, float* __restrict__ b_eff)
{
    const float* W1he = W1 + 256 * 128;
    if (blockIdx.x == 32) {
        const int n = threadIdx.x;
        if (n < 128) {
            float s = b_att1[n];
            for (int k = 0; k < 128; ++k) s = fmaf(b_edge[k], W1he[k * 128 + n], s);
            b_eff[n] = s;
        }
        return;
    }
    const int idx = blockIdx.x * 256 + threadIdx.x;
    const int row = idx >> 7, n = idx & 127;
    float s = 0.f;
    for (int k = 0; k < 128; ++k) s = fmaf(W_edge[row * 128 + k], W1he[k * 128 + n], s);
    Wc[idx] = s;
}

// ---------------------------------------------------------------------------
// Setup B: pack B-operand fragments in MFMA lane order, bf16.
// ---------------------------------------------------------------------------
__global__ __launch_bounds__(256) void k_pack(
    const float* __restrict__ W1, const float* __restrict__ Wc,
    ushort* __restrict__ pack)
{
    const int idx = blockIdx.x * 256 + threadIdx.x;   // 0..40959
    const int j = idx & 7, lane = (idx >> 3) & 63, nt = (idx >> 9) & 7, k0 = idx >> 12;
    const int k = k0 * 32 + (lane >> 4) * 8 + j;
    const int n = nt * 16 + (lane & 15);
    const float v = (k < 256) ? W1[k * 128 + n] : Wc[(k - 256) * 128 + n];
    pack[idx] = f2bf(v);
}

// ---------------------------------------------------------------------------
// K2: per-edge attention p = exp(tanh(cat@W1 + b)@W2 + b2) via MFMA.
// ---------------------------------------------------------------------------
__global__ __launch_bounds__(256) void k_edge_att_mfma(
    const int* __restrict__ srcI, const int* __restrict__ dstI,
    const float* __restrict__ EF, const ushort* __restrict__ Hb,
    const ushort* __restrict__ Bpack, const float* __restrict__ b_eff,
    const float* __restrict__ W2, const float* __restrict__ b2,
    float* __restrict__ att_exp)
{
    const int tid = threadIdx.x;
    const int wave = tid >> 6, lane = tid & 63;
    const int r = lane & 15, g = lane >> 4;
    const int ebase = blockIdx.x * 64 + wave * 16;
    const int e = ebase + r;

    const int s_idx = srcI[e], d_idx = dstI[e];
    const ushort* rowS = Hb + (size_t)s_idx * 128 + g * 8;
    const ushort* rowD = Hb + (size_t)d_idx * 128 + g * 8;
    const float*  rowE = EF + (size_t)e * 64 + g * 8;
    const bf16x8* Bp = reinterpret_cast<const bf16x8*>(Bpack);

    f32x4 acc[8];
#pragma unroll
    for (int nt = 0; nt < 8; ++nt) {
        const float bv = b_eff[nt * 16 + r];
        acc[nt] = (f32x4){bv, bv, bv, bv};
    }

#pragma unroll
    for (int k0 = 0; k0 < 4; ++k0) {
        const bf16x8 a = *reinterpret_cast<const bf16x8*>(rowS + k0 * 32);
#pragma unroll
        for (int nt = 0; nt < 8; ++nt)
            acc[nt] = __builtin_amdgcn_mfma_f32_16x16x32_bf16(
                a, Bp[(k0 * 8 + nt) * 64 + lane], acc[nt], 0, 0, 0);
    }
#pragma unroll
    for (int k0 = 0; k0 < 4; ++k0) {
        const bf16x8 a = *reinterpret_cast<const bf16x8*>(rowD + k0 * 32);
#pragma unroll
        for (int nt = 0; nt < 8; ++nt)
            acc[nt] = __builtin_amdgcn_mfma_f32_16x16x32_bf16(
                a, Bp[((k0 + 4) * 8 + nt) * 64 + lane], acc[nt], 0, 0, 0);
    }
#pragma unroll
    for (int k0 = 0; k0 < 2; ++k0) {
        const float4 e0 = *reinterpret_cast<const float4*>(rowE + k0 * 32);
        const float4 e1 = *reinterpret_cast<const float4*>(rowE + k0 * 32 + 4);
        bf16x8 a;
        a[0] = (short)f2bf(e0.x); a[1] = (short)f2bf(e0.y);
        a[2] = (short)f2bf(e0.z); a[3] = (short)f2bf(e0.w);
        a[4] = (short)f2bf(e1.x); a[5] = (short)f2bf(e1.y);
        a[6] = (short)f2bf(e1.z); a[7] = (short)f2bf(e1.w);
#pragma unroll
        for (int nt = 0; nt < 8; ++nt)
            acc[nt] = __builtin_amdgcn_mfma_f32_16x16x32_bf16(
                a, Bp[((k0 + 8) * 8 + nt) * 64 + lane], acc[nt], 0, 0, 0);
    }

    float part[4] = {0.f, 0.f, 0.f, 0.f};
#pragma unroll
    for (int nt = 0; nt < 8; ++nt) {
        const float w2v = W2[nt * 16 + r];
#pragma unroll
        for (int q = 0; q < 4; ++q)
            part[q] = fmaf(tanhf(acc[nt][q]), w2v, part[q]);
    }
#pragma unroll
    for (int m = 1; m <= 8; m <<= 1) {
#pragma unroll
        for (int q = 0; q < 4; ++q) part[q] += __shfl_xor(part[q], m, 64);
    }
    if (r == 0) {
        const float bb2 = b2[0];
#pragma unroll
        for (int q = 0; q < 4; ++q)
            att_exp[ebase + g * 4 + q] = expf(part[q] + bb2);
    }
}

// ---------------------------------------------------------------------------
// CSR build: histogram -> single-block scan -> fill (p,dst) in segment order
// ---------------------------------------------------------------------------
__global__ __launch_bounds__(256) void k_hist(
    const int* __restrict__ srcI, int* __restrict__ cnt)
{
    const int e = blockIdx.x * 256 + threadIdx.x;
    atomicAdd(&cnt[srcI[e]], 1);
}

__global__ __launch_bounds__(1024) void k_scan(
    const int* __restrict__ cnt, int* __restrict__ rowptr)
{
    __shared__ int wsum[16];
    __shared__ int carry;
    const int tid = threadIdx.x, lane = tid & 63, wid = tid >> 6;
    if (tid == 0) { carry = 0; rowptr[0] = 0; }
    __syncthreads();
    for (int base = 0; base < N_NODES; base += 1024) {
        const int i = base + tid;
        int v = (i < N_NODES) ? cnt[i] : 0;
#pragma unroll
        for (int d = 1; d < 64; d <<= 1) {
            const int t = __shfl_up(v, d, 64);
            if (lane >= d) v += t;
        }
        if (lane == 63) wsum[wid] = v;
        __syncthreads();
        if (wid == 0 && lane < 16) {
            int w = wsum[lane];
#pragma unroll
            for (int d = 1; d < 16; d <<= 1) {
                const int t = __shfl_up(w, d, 16);
                if ((lane & 15) >= d) w += t;
            }
            wsum[lane] = w;
        }
        __syncthreads();
        const int off = (wid == 0) ? 0 : wsum[wid - 1];
        const int res = carry + off + v;
        if (i < N_NODES) rowptr[i + 1] = res;
        const int total = wsum[15];
        __syncthreads();
        if (tid == 0) carry += total;
        __syncthreads();
    }
}

__global__ __launch_bounds__(256) void k_fill(
    const int* __restrict__ srcI, const int* __restrict__ dstI,
    const float* __restrict__ att_exp, const int* __restrict__ rowptr,
    int* __restrict__ cursor, float* __restrict__ csr_p, int* __restrict__ csr_d)
{
    const int e = blockIdx.x * 256 + threadIdx.x;
    const int s = srcI[e];
    const int pos = rowptr[s] + atomicAdd(&cursor[s], 1);
    csr_p[pos] = att_exp[e];
    csr_d[pos] = dstI[e];
}

// ---------------------------------------------------------------------------
// K3: per-node gather-aggregate: agg[n] = sum(p*h[dst]) / sum(p)
// one block per node, 8 edge-slots x 32 col-threads (float4 cols)
// ---------------------------------------------------------------------------
__global__ __launch_bounds__(256) void k_agg(
    const int* __restrict__ rowptr, const float* __restrict__ csr_p,
    const int* __restrict__ csr_d, const ushort* __restrict__ Hb,
    float* __restrict__ agg)
{
    __shared__ float4 red[8][32];
    __shared__ float sred[8];
    const int tid = threadIdx.x, tc = tid & 31, slot = tid >> 5;
    const int n = blockIdx.x;
    const int beg = rowptr[n], end = rowptr[n + 1];

    float4 v = {0.f, 0.f, 0.f, 0.f};
    float sp = 0.f;
    for (int j = beg + slot; j < end; j += 8) {
        const float p = csr_p[j];
        const int d = csr_d[j];
        const ushort4 hv = *reinterpret_cast<const ushort4*>(Hb + (size_t)d * 128 + tc * 4);
        v.x = fmaf(p, bf2f(hv.x), v.x);
        v.y = fmaf(p, bf2f(hv.y), v.y);
        v.z = fmaf(p, bf2f(hv.z), v.z);
        v.w = fmaf(p, bf2f(hv.w), v.w);
        sp += p;
    }
    red[slot][tc] = v;
    if (tc == 0) sred[slot] = sp;
    __syncthreads();
    if (tid < 32) {
        float4 a = red[0][tid];
        float S = sred[0];
#pragma unroll
        for (int s = 1; s < 8; ++s) {
            const float4 b = red[s][tid];
            a.x += b.x; a.y += b.y; a.z += b.z; a.w += b.w;
            S += sred[s];
        }
        const float inv = (end > beg) ? 1.f / S : 0.f;
        const float4 o = {a.x * inv, a.y * inv, a.z * inv, a.w * inv};
        reinterpret_cast<float4*>(agg)[(size_t)n * 32 + tid] = o;
    }
}

// ---------------------------------------------------------------------------
// K4: o = agg @ W_out + b_out ; LayerNorm ; ReLU
// ---------------------------------------------------------------------------
__global__ __launch_bounds__(512) void k_out_ln(
    const float* __restrict__ AGG, const float* __restrict__ W,
    const float* __restrict__ b, const float* __restrict__ gamma,
    const float* __restrict__ beta, float* __restrict__ OUT)
{
    __shared__ float xs[4 * 128];
    __shared__ float red[8][2];
    const int tid = threadIdx.x;
    const int col = tid & 127, g = tid >> 7;
    const int node = blockIdx.x * 4 + g;

    xs[tid] = AGG[(size_t)node * 128 + col];
    __syncthreads();

    float acc = b[col];
    for (int k = 0; k < 128; ++k)
        acc = fmaf(xs[g * 128 + k], W[k * 128 + col], acc);

    float s1 = acc, s2 = acc * acc;
#pragma unroll
    for (int m = 1; m < 64; m <<= 1) {
        s1 += __shfl_xor(s1, m, 64);
        s2 += __shfl_xor(s2, m, 64);
    }
    const int wid = tid >> 6;
    if ((tid & 63) == 0) { red[wid][0] = s1; red[wid][1] = s2; }
    __syncthreads();

    const float S1 = red[2 * g][0] + red[2 * g + 1][0];
    const float S2 = red[2 * g][1] + red[2 * g + 1][1];
    const float mu = S1 * (1.f / 128.f);
    const float var = S2 * (1.f / 128.f) - mu * mu;
    const float rr = rsqrtf(var + 1e-5f);
    const float o = (acc - mu) * rr * gamma[col] + beta[col];
    OUT[(size_t)node * 128 + col] = o > 0.f ? o : 0.f;
}

// ---------------------------------------------------------------------------
extern "C" void kernel_launch(void* const* d_in, const int* in_sizes, int n_in,
                              void* d_out, int out_size, void* d_ws, size_t ws_size,
                              hipStream_t stream)
{
    const float* node_features = (const float*)d_in[0];
    const int*   edge_index    = (const int*)d_in[1];
    const float* edge_features = (const float*)d_in[2];
    const float* W_node  = (const float*)d_in[3];
    const float* b_node  = (const float*)d_in[4];
    const float* W_edge  = (const float*)d_in[5];
    const float* b_edge  = (const float*)d_in[6];
    const float* W_att1  = (const float*)d_in[7];
    const float* b_att1  = (const float*)d_in[8];
    const float* W_att2  = (const float*)d_in[9];
    const float* b_att2  = (const float*)d_in[10];
    const float* W_out   = (const float*)d_in[11];
    const float* b_out   = (const float*)d_in[12];
    const float* ln_gamma = (const float*)d_in[13];
    const float* ln_beta  = (const float*)d_in[14];
    float* out = (float*)d_out;

    // workspace layout (byte offsets, 16B-aligned)
    char* ws = (char*)d_ws;
    ushort* hb      = (ushort*)(ws);                   // 10,240,000 B
    float*  att_exp = (float*)(ws + 10240000);         //  2,560,000 B
    float*  csr_p   = (float*)(ws + 12800000);         //  2,560,000 B
    int*    csr_d   = (int*)(ws + 15360000);           //  2,560,000 B
    int*    rowptr  = (int*)(ws + 17920000);           //    160,004 B
    int*    cnt     = (int*)(ws + 18080016);           //    160,000 B
    int*    cursor  = (int*)(ws + 18240016);           //    160,000 B (contiguous after cnt)
    float*  agg     = (float*)(ws + 18400016);         // 20,480,000 B
    float*  Wc      = (float*)(ws + 38880016);         //     32,768 B
    float*  b_eff   = (float*)(ws + 38912784);         //        512 B
    ushort* pack    = (ushort*)(ws + 38913296);        //     81,920 B

    const int* srcI = edge_index;
    const int* dstI = edge_index + N_EDGES;

    // zero histogram + fill cursors (contiguous)
    hipMemsetAsync(cnt, 0, 320000, stream);

    k_node_gemm<<<N_NODES / 16, 256, 0, stream>>>(node_features, W_node, b_node, hb);
    k_wcomb<<<33, 256, 0, stream>>>(W_edge, W_att1, b_att1, b_edge, Wc, b_eff);
    k_pack<<<160, 256, 0, stream>>>(W_att1, Wc, pack);
    k_hist<<<N_EDGES / 256, 256, 0, stream>>>(srcI, cnt);
    k_scan<<<1, 1024, 0, stream>>>(cnt, rowptr);
    k_edge_att_mfma<<<N_EDGES / 64, 256, 0, stream>>>(srcI, dstI, edge_features, hb,
                                                      pack, b_eff, W_att2, b_att2,
                                                      att_exp);
    k_fill<<<N_EDGES / 256, 256, 0, stream>>>(srcI, dstI, att_exp, rowptr,
                                              cursor, csr_p, csr_d);
    k_agg<<<N_NODES, 256, 0, stream>>>(rowptr, csr_p, csr_d, hb, agg);
    k_out_ln<<<N_NODES / 4, 512, 0, stream>>>(agg, W_out, b_out, ln_gamma, ln_beta, out);
}

// Round 8
// 442.606 us; speedup vs baseline: 5.2766x; 1.0109x over previous
//
#include <hip/hip_runtime.h>
#include <math.h>

#define N_NODES 40000
#define N_EDGES 640000
#define IN_DIM 128
#define EDGE_DIM 64
#define HID 128

typedef __attribute__((ext_vector_type(8))) short bf16x8;
typedef __attribute__((ext_vector_type(4))) float f32x4;

__device__ __forceinline__ ushort f2bf(float f) {
    unsigned int x = __float_as_uint(f);
    x += 0x7fffu + ((x >> 16) & 1u);
    return (ushort)(x >> 16);
}
__device__ __forceinline__ float bf2f(ushort u) {
    return __uint_as_float(((unsigned int)u) << 16);
}
// tanh(x) = 1 - 2/(e^{2x}+1); e^{2x}=inf -> 1, e^{2x}=0 -> -1 (no NaN)
__device__ __forceinline__ float tanh_fast(float x) {
    return 1.f - __fdividef(2.f, __expf(2.f * x) + 1.f);
}

// ---------------------------------------------------------------------------
// K1: h = node_features @ W_node + b_node ; bf16 output only.
// ---------------------------------------------------------------------------
__global__ __launch_bounds__(256) void k_node_gemm(
    const float* __restrict__ X, const float* __restrict__ W,
    const float* __restrict__ b, ushort* __restrict__ Hb)
{
    __shared__ float xs[16 * 128];
    const int tid = threadIdx.x;
    const int base = blockIdx.x * 16;

    const float4* Xg = reinterpret_cast<const float4*>(X + (size_t)base * 128);
    float4* xs4 = reinterpret_cast<float4*>(xs);
#pragma unroll
    for (int i = 0; i < 2; ++i) xs4[tid + 256 * i] = Xg[tid + 256 * i];
    __syncthreads();

    const int col = tid & 127, g = tid >> 7;
    float acc[8];
#pragma unroll
    for (int i = 0; i < 8; ++i) acc[i] = 0.f;

    for (int k = 0; k < 128; ++k) {
        const float w = W[k * 128 + col];
#pragma unroll
        for (int i = 0; i < 8; ++i) acc[i] = fmaf(xs[(g + 2 * i) * 128 + k], w, acc[i]);
    }
    const float bb = b[col];
#pragma unroll
    for (int i = 0; i < 8; ++i)
        Hb[(size_t)(base + g + 2 * i) * 128 + col] = f2bf(acc[i] + bb);
}

// ---------------------------------------------------------------------------
// Setup A: W_comb = W_edge @ W1[256:384]; b_eff = b_att1 + b_edge @ W1he
// ---------------------------------------------------------------------------
__global__ __launch_bounds__(256) void k_wcomb(
    const float* __restrict__ W_edge, const float* __restrict__ W1,
    const float* __restrict__ b_att1, const float* __restrict__ b_edge,
    float* __restrict__ Wc, float* __restrict__ b_eff)
{
    const float* W1he = W1 + 256 * 128;
    if (blockIdx.x == 32) {
        const int n = threadIdx.x;
        if (n < 128) {
            float s = b_att1[n];
            for (int k = 0; k < 128; ++k) s = fmaf(b_edge[k], W1he[k * 128 + n], s);
            b_eff[n] = s;
        }
        return;
    }
    const int idx = blockIdx.x * 256 + threadIdx.x;
    const int row = idx >> 7, n = idx & 127;
    float s = 0.f;
    for (int k = 0; k < 128; ++k) s = fmaf(W_edge[row * 128 + k], W1he[k * 128 + n], s);
    Wc[idx] = s;
}

// ---------------------------------------------------------------------------
// Setup B: pack B-operand fragments in MFMA lane order, bf16.
// ---------------------------------------------------------------------------
__global__ __launch_bounds__(256) void k_pack(
    const float* __restrict__ W1, const float* __restrict__ Wc,
    ushort* __restrict__ pack)
{
    const int idx = blockIdx.x * 256 + threadIdx.x;   // 0..40959
    const int j = idx & 7, lane = (idx >> 3) & 63, nt = (idx >> 9) & 7, k0 = idx >> 12;
    const int k = k0 * 32 + (lane >> 4) * 8 + j;
    const int n = nt * 16 + (lane & 15);
    const float v = (k < 256) ? W1[k * 128 + n] : Wc[(k - 256) * 128 + n];
    pack[idx] = f2bf(v);
}

// ---------------------------------------------------------------------------
// K2: per-edge attention p = exp(tanh(cat@W1 + b)@W2 + b2) via MFMA.
// Wave = 32 edges (two 16-row m-tiles sharing each B fragment). 4 waves/block.
// ---------------------------------------------------------------------------
__global__ __launch_bounds__(256) void k_edge_att_mfma(
    const int* __restrict__ srcI, const int* __restrict__ dstI,
    const float* __restrict__ EF, const ushort* __restrict__ Hb,
    const ushort* __restrict__ Bpack, const float* __restrict__ b_eff,
    const float* __restrict__ W2, const float* __restrict__ b2,
    float* __restrict__ att_exp)
{
    const int tid = threadIdx.x;
    const int wave = tid >> 6, lane = tid & 63;
    const int r = lane & 15, g = lane >> 4;
    const int ebase = blockIdx.x * 128 + wave * 32;
    const int e0 = ebase + r, e1 = ebase + 16 + r;

    const int s0 = srcI[e0], d0 = dstI[e0];
    const int s1 = srcI[e1], d1 = dstI[e1];
    const ushort* rowS0 = Hb + (size_t)s0 * 128 + g * 8;
    const ushort* rowD0 = Hb + (size_t)d0 * 128 + g * 8;
    const ushort* rowS1 = Hb + (size_t)s1 * 128 + g * 8;
    const ushort* rowD1 = Hb + (size_t)d1 * 128 + g * 8;
    const float*  rowE0 = EF + (size_t)e0 * 64 + g * 8;
    const float*  rowE1 = EF + (size_t)e1 * 64 + g * 8;
    const bf16x8* Bp = reinterpret_cast<const bf16x8*>(Bpack);

    f32x4 acc0[8], acc1[8];
#pragma unroll
    for (int nt = 0; nt < 8; ++nt) {
        const float bv = b_eff[nt * 16 + r];
        acc0[nt] = (f32x4){bv, bv, bv, bv};
        acc1[nt] = (f32x4){bv, bv, bv, bv};
    }

    // chunk 1: h_src (k0 = 0..3)
#pragma unroll
    for (int k0 = 0; k0 < 4; ++k0) {
        const bf16x8 a0 = *reinterpret_cast<const bf16x8*>(rowS0 + k0 * 32);
        const bf16x8 a1 = *reinterpret_cast<const bf16x8*>(rowS1 + k0 * 32);
#pragma unroll
        for (int nt = 0; nt < 8; ++nt) {
            const bf16x8 bfrag = Bp[(k0 * 8 + nt) * 64 + lane];
            acc0[nt] = __builtin_amdgcn_mfma_f32_16x16x32_bf16(a0, bfrag, acc0[nt], 0, 0, 0);
            acc1[nt] = __builtin_amdgcn_mfma_f32_16x16x32_bf16(a1, bfrag, acc1[nt], 0, 0, 0);
        }
    }
    // chunk 2: h_dst (k0 = 4..7)
#pragma unroll
    for (int k0 = 0; k0 < 4; ++k0) {
        const bf16x8 a0 = *reinterpret_cast<const bf16x8*>(rowD0 + k0 * 32);
        const bf16x8 a1 = *reinterpret_cast<const bf16x8*>(rowD1 + k0 * 32);
#pragma unroll
        for (int nt = 0; nt < 8; ++nt) {
            const bf16x8 bfrag = Bp[((k0 + 4) * 8 + nt) * 64 + lane];
            acc0[nt] = __builtin_amdgcn_mfma_f32_16x16x32_bf16(a0, bfrag, acc0[nt], 0, 0, 0);
            acc1[nt] = __builtin_amdgcn_mfma_f32_16x16x32_bf16(a1, bfrag, acc1[nt], 0, 0, 0);
        }
    }
    // chunk 3: EF fp32 -> bf16 on the fly (k0 = 8..9)
#pragma unroll
    for (int k0 = 0; k0 < 2; ++k0) {
        const float4 p0 = *reinterpret_cast<const float4*>(rowE0 + k0 * 32);
        const float4 p1 = *reinterpret_cast<const float4*>(rowE0 + k0 * 32 + 4);
        const float4 q0 = *reinterpret_cast<const float4*>(rowE1 + k0 * 32);
        const float4 q1 = *reinterpret_cast<const float4*>(rowE1 + k0 * 32 + 4);
        bf16x8 a0, a1;
        a0[0] = (short)f2bf(p0.x); a0[1] = (short)f2bf(p0.y);
        a0[2] = (short)f2bf(p0.z); a0[3] = (short)f2bf(p0.w);
        a0[4] = (short)f2bf(p1.x); a0[5] = (short)f2bf(p1.y);
        a0[6] = (short)f2bf(p1.z); a0[7] = (short)f2bf(p1.w);
        a1[0] = (short)f2bf(q0.x); a1[1] = (short)f2bf(q0.y);
        a1[2] = (short)f2bf(q0.z); a1[3] = (short)f2bf(q0.w);
        a1[4] = (short)f2bf(q1.x); a1[5] = (short)f2bf(q1.y);
        a1[6] = (short)f2bf(q1.z); a1[7] = (short)f2bf(q1.w);
#pragma unroll
        for (int nt = 0; nt < 8; ++nt) {
            const bf16x8 bfrag = Bp[((k0 + 8) * 8 + nt) * 64 + lane];
            acc0[nt] = __builtin_amdgcn_mfma_f32_16x16x32_bf16(a0, bfrag, acc0[nt], 0, 0, 0);
            acc1[nt] = __builtin_amdgcn_mfma_f32_16x16x32_bf16(a1, bfrag, acc1[nt], 0, 0, 0);
        }
    }

    // epilogue: a = tanh(z)@W2 ; reduce over col groups ; p = exp(a + b2)
    float part0[4] = {0.f, 0.f, 0.f, 0.f};
    float part1[4] = {0.f, 0.f, 0.f, 0.f};
#pragma unroll
    for (int nt = 0; nt < 8; ++nt) {
        const float w2v = W2[nt * 16 + r];
#pragma unroll
        for (int q = 0; q < 4; ++q) {
            part0[q] = fmaf(tanh_fast(acc0[nt][q]), w2v, part0[q]);
            part1[q] = fmaf(tanh_fast(acc1[nt][q]), w2v, part1[q]);
        }
    }
#pragma unroll
    for (int m = 1; m <= 8; m <<= 1) {
#pragma unroll
        for (int q = 0; q < 4; ++q) {
            part0[q] += __shfl_xor(part0[q], m, 64);
            part1[q] += __shfl_xor(part1[q], m, 64);
        }
    }
    if (r == 0) {
        const float bb2 = b2[0];
#pragma unroll
        for (int q = 0; q < 4; ++q) {
            att_exp[ebase + g * 4 + q]      = __expf(part0[q] + bb2);
            att_exp[ebase + 16 + g * 4 + q] = __expf(part1[q] + bb2);
        }
    }
}

// ---------------------------------------------------------------------------
// CSR build: histogram -> single-block scan -> fill (p,dst) in segment order
// ---------------------------------------------------------------------------
__global__ __launch_bounds__(256) void k_hist(
    const int* __restrict__ srcI, int* __restrict__ cnt)
{
    const int e = blockIdx.x * 256 + threadIdx.x;
    atomicAdd(&cnt[srcI[e]], 1);
}

__global__ __launch_bounds__(1024) void k_scan(
    const int* __restrict__ cnt, int* __restrict__ rowptr)
{
    __shared__ int wsum[16];
    __shared__ int carry;
    const int tid = threadIdx.x, lane = tid & 63, wid = tid >> 6;
    if (tid == 0) { carry = 0; rowptr[0] = 0; }
    __syncthreads();
    for (int base = 0; base < N_NODES; base += 1024) {
        const int i = base + tid;
        int v = (i < N_NODES) ? cnt[i] : 0;
#pragma unroll
        for (int d = 1; d < 64; d <<= 1) {
            const int t = __shfl_up(v, d, 64);
            if (lane >= d) v += t;
        }
        if (lane == 63) wsum[wid] = v;
        __syncthreads();
        if (wid == 0 && lane < 16) {
            int w = wsum[lane];
#pragma unroll
            for (int d = 1; d < 16; d <<= 1) {
                const int t = __shfl_up(w, d, 16);
                if ((lane & 15) >= d) w += t;
            }
            wsum[lane] = w;
        }
        __syncthreads();
        const int off = (wid == 0) ? 0 : wsum[wid - 1];
        const int res = carry + off + v;
        if (i < N_NODES) rowptr[i + 1] = res;
        const int total = wsum[15];
        __syncthreads();
        if (tid == 0) carry += total;
        __syncthreads();
    }
}

__global__ __launch_bounds__(256) void k_fill(
    const int* __restrict__ srcI, const int* __restrict__ dstI,
    const float* __restrict__ att_exp, const int* __restrict__ rowptr,
    int* __restrict__ cursor, float* __restrict__ csr_p, int* __restrict__ csr_d)
{
    const int e = blockIdx.x * 256 + threadIdx.x;
    const int s = srcI[e];
    const int pos = rowptr[s] + atomicAdd(&cursor[s], 1);
    csr_p[pos] = att_exp[e];
    csr_d[pos] = dstI[e];
}

// ---------------------------------------------------------------------------
// K3: per-node gather-aggregate: agg[n] = sum(p*h[dst]) / sum(p)
// ---------------------------------------------------------------------------
__global__ __launch_bounds__(256) void k_agg(
    const int* __restrict__ rowptr, const float* __restrict__ csr_p,
    const int* __restrict__ csr_d, const ushort* __restrict__ Hb,
    float* __restrict__ agg)
{
    __shared__ float4 red[8][32];
    __shared__ float sred[8];
    const int tid = threadIdx.x, tc = tid & 31, slot = tid >> 5;
    const int n = blockIdx.x;
    const int beg = rowptr[n], end = rowptr[n + 1];

    float4 v = {0.f, 0.f, 0.f, 0.f};
    float sp = 0.f;
    for (int j = beg + slot; j < end; j += 8) {
        const float p = csr_p[j];
        const int d = csr_d[j];
        const ushort4 hv = *reinterpret_cast<const ushort4*>(Hb + (size_t)d * 128 + tc * 4);
        v.x = fmaf(p, bf2f(hv.x), v.x);
        v.y = fmaf(p, bf2f(hv.y), v.y);
        v.z = fmaf(p, bf2f(hv.z), v.z);
        v.w = fmaf(p, bf2f(hv.w), v.w);
        sp += p;
    }
    red[slot][tc] = v;
    if (tc == 0) sred[slot] = sp;
    __syncthreads();
    if (tid < 32) {
        float4 a = red[0][tid];
        float S = sred[0];
#pragma unroll
        for (int s = 1; s < 8; ++s) {
            const float4 b = red[s][tid];
            a.x += b.x; a.y += b.y; a.z += b.z; a.w += b.w;
            S += sred[s];
        }
        const float inv = (end > beg) ? 1.f / S : 0.f;
        const float4 o = {a.x * inv, a.y * inv, a.z * inv, a.w * inv};
        reinterpret_cast<float4*>(agg)[(size_t)n * 32 + tid] = o;
    }
}

// ---------------------------------------------------------------------------
// K4: o = agg @ W_out + b_out ; LayerNorm ; ReLU
// ---------------------------------------------------------------------------
__global__ __launch_bounds__(512) void k_out_ln(
    const float* __restrict__ AGG, const float* __restrict__ W,
    const float* __restrict__ b, const float* __restrict__ gamma,
    const float* __restrict__ beta, float* __restrict__ OUT)
{
    __shared__ float xs[4 * 128];
    __shared__ float red[8][2];
    const int tid = threadIdx.x;
    const int col = tid & 127, g = tid >> 7;
    const int node = blockIdx.x * 4 + g;

    xs[tid] = AGG[(size_t)node * 128 + col];
    __syncthreads();

    float acc = b[col];
    for (int k = 0; k < 128; ++k)
        acc = fmaf(xs[g * 128 + k], W[k * 128 + col], acc);

    float s1 = acc, s2 = acc * acc;
#pragma unroll
    for (int m = 1; m < 64; m <<= 1) {
        s1 += __shfl_xor(s1, m, 64);
        s2 += __shfl_xor(s2, m, 64);
    }
    const int wid = tid >> 6;
    if ((tid & 63) == 0) { red[wid][0] = s1; red[wid][1] = s2; }
    __syncthreads();

    const float S1 = red[2 * g][0] + red[2 * g + 1][0];
    const float S2 = red[2 * g][1] + red[2 * g + 1][1];
    const float mu = S1 * (1.f / 128.f);
    const float var = S2 * (1.f / 128.f) - mu * mu;
    const float rr = rsqrtf(var + 1e-5f);
    const float o = (acc - mu) * rr * gamma[col] + beta[col];
    OUT[(size_t)node * 128 + col] = o > 0.f ? o : 0.f;
}

// ---------------------------------------------------------------------------
extern "C" void kernel_launch(void* const* d_in, const int* in_sizes, int n_in,
                              void* d_out, int out_size, void* d_ws, size_t ws_size,
                              hipStream_t stream)
{
    const float* node_features = (const float*)d_in[0];
    const int*   edge_index    = (const int*)d_in[1];
    const float* edge_features = (const float*)d_in[2];
    const float* W_node  = (const float*)d_in[3];
    const float* b_node  = (const float*)d_in[4];
    const float* W_edge  = (const float*)d_in[5];
    const float* b_edge  = (const float*)d_in[6];
    const float* W_att1  = (const float*)d_in[7];
    const float* b_att1  = (const float*)d_in[8];
    const float* W_att2  = (const float*)d_in[9];
    const float* b_att2  = (const float*)d_in[10];
    const float* W_out   = (const float*)d_in[11];
    const float* b_out   = (const float*)d_in[12];
    const float* ln_gamma = (const float*)d_in[13];
    const float* ln_beta  = (const float*)d_in[14];
    float* out = (float*)d_out;

    // workspace layout (byte offsets, 16B-aligned)
    char* ws = (char*)d_ws;
    ushort* hb      = (ushort*)(ws);                   // 10,240,000 B
    float*  att_exp = (float*)(ws + 10240000);         //  2,560,000 B
    float*  csr_p   = (float*)(ws + 12800000);         //  2,560,000 B
    int*    csr_d   = (int*)(ws + 15360000);           //  2,560,000 B
    int*    rowptr  = (int*)(ws + 17920000);           //    160,004 B
    int*    cnt     = (int*)(ws + 18080016);           //    160,000 B
    int*    cursor  = (int*)(ws + 18240016);           //    160,000 B (contiguous after cnt)
    float*  agg     = (float*)(ws + 18400016);         // 20,480,000 B
    float*  Wc      = (float*)(ws + 38880016);         //     32,768 B
    float*  b_eff   = (float*)(ws + 38912784);         //        512 B
    ushort* pack    = (ushort*)(ws + 38913296);        //     81,920 B

    const int* srcI = edge_index;
    const int* dstI = edge_index + N_EDGES;

    // zero histogram + fill cursors (contiguous)
    hipMemsetAsync(cnt, 0, 320000, stream);

    k_node_gemm<<<N_NODES / 16, 256, 0, stream>>>(node_features, W_node, b_node, hb);
    k_wcomb<<<33, 256, 0, stream>>>(W_edge, W_att1, b_att1, b_edge, Wc, b_eff);
    k_pack<<<160, 256, 0, stream>>>(W_att1, Wc, pack);
    k_hist<<<N_EDGES / 256, 256, 0, stream>>>(srcI, cnt);
    k_scan<<<1, 1024, 0, stream>>>(cnt, rowptr);
    k_edge_att_mfma<<<N_EDGES / 128, 256, 0, stream>>>(srcI, dstI, edge_features, hb,
                                                       pack, b_eff, W_att2, b_att2,
                                                       att_exp);
    k_fill<<<N_EDGES / 256, 256, 0, stream>>>(srcI, dstI, att_exp, rowptr,
                                              cursor, csr_p, csr_d);
    k_agg<<<N_NODES, 256, 0, stream>>>(rowptr, csr_p, csr_d, hb, agg);
    k_out_ln<<<N_NODES / 4, 512, 0, stream>>>(agg, W_out, b_out, ln_gamma, ln_beta, out);
}

// Round 9
// 419.322 us; speedup vs baseline: 5.5696x; 1.0555x over previous
//
#include <hip/hip_runtime.h>
#include <math.h>

#define N_NODES 40000
#define N_EDGES 640000
#define IN_DIM 128
#define EDGE_DIM 64
#define HID 128

typedef __attribute__((ext_vector_type(8))) short bf16x8;
typedef __attribute__((ext_vector_type(4))) float f32x4;

__device__ __forceinline__ ushort f2bf(float f) {
    unsigned int x = __float_as_uint(f);
    x += 0x7fffu + ((x >> 16) & 1u);
    return (ushort)(x >> 16);
}
__device__ __forceinline__ float bf2f(ushort u) {
    return __uint_as_float(((unsigned int)u) << 16);
}
// tanh(x) = 1 - 2/(e^{2x}+1); e^{2x}=inf -> 1, e^{2x}=0 -> -1 (no NaN)
__device__ __forceinline__ float tanh_fast(float x) {
    return 1.f - __fdividef(2.f, __expf(2.f * x) + 1.f);
}

// ---------------------------------------------------------------------------
// K1: h = node_features @ W_node + b_node ; bf16 output only.
// ---------------------------------------------------------------------------
__global__ __launch_bounds__(256) void k_node_gemm(
    const float* __restrict__ X, const float* __restrict__ W,
    const float* __restrict__ b, ushort* __restrict__ Hb)
{
    __shared__ float xs[16 * 128];
    const int tid = threadIdx.x;
    const int base = blockIdx.x * 16;

    const float4* Xg = reinterpret_cast<const float4*>(X + (size_t)base * 128);
    float4* xs4 = reinterpret_cast<float4*>(xs);
#pragma unroll
    for (int i = 0; i < 2; ++i) xs4[tid + 256 * i] = Xg[tid + 256 * i];
    __syncthreads();

    const int col = tid & 127, g = tid >> 7;
    float acc[8];
#pragma unroll
    for (int i = 0; i < 8; ++i) acc[i] = 0.f;

    for (int k = 0; k < 128; ++k) {
        const float w = W[k * 128 + col];
#pragma unroll
        for (int i = 0; i < 8; ++i) acc[i] = fmaf(xs[(g + 2 * i) * 128 + k], w, acc[i]);
    }
    const float bb = b[col];
#pragma unroll
    for (int i = 0; i < 8; ++i)
        Hb[(size_t)(base + g + 2 * i) * 128 + col] = f2bf(acc[i] + bb);
}

// ---------------------------------------------------------------------------
// Setup A: W_comb = W_edge @ W1[256:384]; b_eff = b_att1 + b_edge @ W1he
// ---------------------------------------------------------------------------
__global__ __launch_bounds__(256) void k_wcomb(
    const float* __restrict__ W_edge, const float* __restrict__ W1,
    const float* __restrict__ b_att1, const float* __restrict__ b_edge,
    float* __restrict__ Wc, float* __restrict__ b_eff)
{
    const float* W1he = W1 + 256 * 128;
    if (blockIdx.x == 32) {
        const int n = threadIdx.x;
        if (n < 128) {
            float s = b_att1[n];
            for (int k = 0; k < 128; ++k) s = fmaf(b_edge[k], W1he[k * 128 + n], s);
            b_eff[n] = s;
        }
        return;
    }
    const int idx = blockIdx.x * 256 + threadIdx.x;
    const int row = idx >> 7, n = idx & 127;
    float s = 0.f;
    for (int k = 0; k < 128; ++k) s = fmaf(W_edge[row * 128 + k], W1he[k * 128 + n], s);
    Wc[idx] = s;
}

// ---------------------------------------------------------------------------
// Setup B: pack B-operand fragments in MFMA lane order, bf16.
// pack[k0][nt][lane] : bf16x8 per (k0,nt,lane); k = k0*32+(lane>>4)*8+j, n = nt*16+(lane&15)
// ---------------------------------------------------------------------------
__global__ __launch_bounds__(256) void k_pack(
    const float* __restrict__ W1, const float* __restrict__ Wc,
    ushort* __restrict__ pack)
{
    const int idx = blockIdx.x * 256 + threadIdx.x;   // 0..40959
    const int j = idx & 7, lane = (idx >> 3) & 63, nt = (idx >> 9) & 7, k0 = idx >> 12;
    const int k = k0 * 32 + (lane >> 4) * 8 + j;
    const int n = nt * 16 + (lane & 15);
    const float v = (k < 256) ? W1[k * 128 + n] : Wc[(k - 256) * 128 + n];
    pack[idx] = f2bf(v);
}

// ---------------------------------------------------------------------------
// K2: per-edge attention p = exp(tanh(cat@W1 + b)@W2 + b2) via MFMA.
// 512 threads = 8 waves; wave = 32 edges (two 16-row m-tiles sharing B frags).
// Full B pack (80 KB) staged in LDS once per block -> B reads are ds_read_b128.
// ---------------------------------------------------------------------------
__global__ __launch_bounds__(512, 4) void k_edge_att_mfma(
    const int* __restrict__ srcI, const int* __restrict__ dstI,
    const float* __restrict__ EF, const ushort* __restrict__ Hb,
    const ushort* __restrict__ Bpack, const float* __restrict__ b_eff,
    const float* __restrict__ W2, const float* __restrict__ b2,
    float* __restrict__ att_exp)
{
    __shared__ ushort bsh[40960];   // 80 KB: full packed B

    const int tid = threadIdx.x;

    // cooperative stage: 5120 x 16B frags / 512 threads = 10 each
    {
        const bf16x8* Bg = reinterpret_cast<const bf16x8*>(Bpack);
        bf16x8* Bs = reinterpret_cast<bf16x8*>(bsh);
#pragma unroll
        for (int i = 0; i < 10; ++i) Bs[tid + 512 * i] = Bg[tid + 512 * i];
    }
    __syncthreads();
    const bf16x8* Bp = reinterpret_cast<const bf16x8*>(bsh);

    const int wave = tid >> 6, lane = tid & 63;
    const int r = lane & 15, g = lane >> 4;
    const int ebase = blockIdx.x * 256 + wave * 32;
    const int e0 = ebase + r, e1 = ebase + 16 + r;

    const int s0 = srcI[e0], d0 = dstI[e0];
    const int s1 = srcI[e1], d1 = dstI[e1];
    const ushort* rowS0 = Hb + (size_t)s0 * 128 + g * 8;
    const ushort* rowD0 = Hb + (size_t)d0 * 128 + g * 8;
    const ushort* rowS1 = Hb + (size_t)s1 * 128 + g * 8;
    const ushort* rowD1 = Hb + (size_t)d1 * 128 + g * 8;
    const float*  rowE0 = EF + (size_t)e0 * 64 + g * 8;
    const float*  rowE1 = EF + (size_t)e1 * 64 + g * 8;

    f32x4 acc0[8], acc1[8];
#pragma unroll
    for (int nt = 0; nt < 8; ++nt) {
        const float bv = b_eff[nt * 16 + r];
        acc0[nt] = (f32x4){bv, bv, bv, bv};
        acc1[nt] = (f32x4){bv, bv, bv, bv};
    }

    // chunk 1: h_src (k0 = 0..3)
#pragma unroll
    for (int k0 = 0; k0 < 4; ++k0) {
        const bf16x8 a0 = *reinterpret_cast<const bf16x8*>(rowS0 + k0 * 32);
        const bf16x8 a1 = *reinterpret_cast<const bf16x8*>(rowS1 + k0 * 32);
#pragma unroll
        for (int nt = 0; nt < 8; ++nt) {
            const bf16x8 bfrag = Bp[(k0 * 8 + nt) * 64 + lane];
            acc0[nt] = __builtin_amdgcn_mfma_f32_16x16x32_bf16(a0, bfrag, acc0[nt], 0, 0, 0);
            acc1[nt] = __builtin_amdgcn_mfma_f32_16x16x32_bf16(a1, bfrag, acc1[nt], 0, 0, 0);
        }
    }
    // chunk 2: h_dst (k0 = 4..7)
#pragma unroll
    for (int k0 = 0; k0 < 4; ++k0) {
        const bf16x8 a0 = *reinterpret_cast<const bf16x8*>(rowD0 + k0 * 32);
        const bf16x8 a1 = *reinterpret_cast<const bf16x8*>(rowD1 + k0 * 32);
#pragma unroll
        for (int nt = 0; nt < 8; ++nt) {
            const bf16x8 bfrag = Bp[((k0 + 4) * 8 + nt) * 64 + lane];
            acc0[nt] = __builtin_amdgcn_mfma_f32_16x16x32_bf16(a0, bfrag, acc0[nt], 0, 0, 0);
            acc1[nt] = __builtin_amdgcn_mfma_f32_16x16x32_bf16(a1, bfrag, acc1[nt], 0, 0, 0);
        }
    }
    // chunk 3: EF fp32 -> bf16 on the fly (k0 = 8..9)
#pragma unroll
    for (int k0 = 0; k0 < 2; ++k0) {
        const float4 p0 = *reinterpret_cast<const float4*>(rowE0 + k0 * 32);
        const float4 p1 = *reinterpret_cast<const float4*>(rowE0 + k0 * 32 + 4);
        const float4 q0 = *reinterpret_cast<const float4*>(rowE1 + k0 * 32);
        const float4 q1 = *reinterpret_cast<const float4*>(rowE1 + k0 * 32 + 4);
        bf16x8 a0, a1;
        a0[0] = (short)f2bf(p0.x); a0[1] = (short)f2bf(p0.y);
        a0[2] = (short)f2bf(p0.z); a0[3] = (short)f2bf(p0.w);
        a0[4] = (short)f2bf(p1.x); a0[5] = (short)f2bf(p1.y);
        a0[6] = (short)f2bf(p1.z); a0[7] = (short)f2bf(p1.w);
        a1[0] = (short)f2bf(q0.x); a1[1] = (short)f2bf(q0.y);
        a1[2] = (short)f2bf(q0.z); a1[3] = (short)f2bf(q0.w);
        a1[4] = (short)f2bf(q1.x); a1[5] = (short)f2bf(q1.y);
        a1[6] = (short)f2bf(q1.z); a1[7] = (short)f2bf(q1.w);
#pragma unroll
        for (int nt = 0; nt < 8; ++nt) {
            const bf16x8 bfrag = Bp[((k0 + 8) * 8 + nt) * 64 + lane];
            acc0[nt] = __builtin_amdgcn_mfma_f32_16x16x32_bf16(a0, bfrag, acc0[nt], 0, 0, 0);
            acc1[nt] = __builtin_amdgcn_mfma_f32_16x16x32_bf16(a1, bfrag, acc1[nt], 0, 0, 0);
        }
    }

    // epilogue: a = tanh(z)@W2 ; reduce over col groups ; p = exp(a + b2)
    float part0[4] = {0.f, 0.f, 0.f, 0.f};
    float part1[4] = {0.f, 0.f, 0.f, 0.f};
#pragma unroll
    for (int nt = 0; nt < 8; ++nt) {
        const float w2v = W2[nt * 16 + r];
#pragma unroll
        for (int q = 0; q < 4; ++q) {
            part0[q] = fmaf(tanh_fast(acc0[nt][q]), w2v, part0[q]);
            part1[q] = fmaf(tanh_fast(acc1[nt][q]), w2v, part1[q]);
        }
    }
#pragma unroll
    for (int m = 1; m <= 8; m <<= 1) {
#pragma unroll
        for (int q = 0; q < 4; ++q) {
            part0[q] += __shfl_xor(part0[q], m, 64);
            part1[q] += __shfl_xor(part1[q], m, 64);
        }
    }
    if (r == 0) {
        const float bb2 = b2[0];
#pragma unroll
        for (int q = 0; q < 4; ++q) {
            att_exp[ebase + g * 4 + q]      = __expf(part0[q] + bb2);
            att_exp[ebase + 16 + g * 4 + q] = __expf(part1[q] + bb2);
        }
    }
}

// ---------------------------------------------------------------------------
// CSR build: histogram -> single-block scan -> fill (p,dst) in segment order
// ---------------------------------------------------------------------------
__global__ __launch_bounds__(256) void k_hist(
    const int* __restrict__ srcI, int* __restrict__ cnt)
{
    const int e = blockIdx.x * 256 + threadIdx.x;
    atomicAdd(&cnt[srcI[e]], 1);
}

__global__ __launch_bounds__(1024) void k_scan(
    const int* __restrict__ cnt, int* __restrict__ rowptr)
{
    __shared__ int wsum[16];
    __shared__ int carry;
    const int tid = threadIdx.x, lane = tid & 63, wid = tid >> 6;
    if (tid == 0) { carry = 0; rowptr[0] = 0; }
    __syncthreads();
    for (int base = 0; base < N_NODES; base += 1024) {
        const int i = base + tid;
        int v = (i < N_NODES) ? cnt[i] : 0;
#pragma unroll
        for (int d = 1; d < 64; d <<= 1) {
            const int t = __shfl_up(v, d, 64);
            if (lane >= d) v += t;
        }
        if (lane == 63) wsum[wid] = v;
        __syncthreads();
        if (wid == 0 && lane < 16) {
            int w = wsum[lane];
#pragma unroll
            for (int d = 1; d < 16; d <<= 1) {
                const int t = __shfl_up(w, d, 16);
                if ((lane & 15) >= d) w += t;
            }
            wsum[lane] = w;
        }
        __syncthreads();
        const int off = (wid == 0) ? 0 : wsum[wid - 1];
        const int res = carry + off + v;
        if (i < N_NODES) rowptr[i + 1] = res;
        const int total = wsum[15];
        __syncthreads();
        if (tid == 0) carry += total;
        __syncthreads();
    }
}

__global__ __launch_bounds__(256) void k_fill(
    const int* __restrict__ srcI, const int* __restrict__ dstI,
    const float* __restrict__ att_exp, const int* __restrict__ rowptr,
    int* __restrict__ cursor, float* __restrict__ csr_p, int* __restrict__ csr_d)
{
    const int e = blockIdx.x * 256 + threadIdx.x;
    const int s = srcI[e];
    const int pos = rowptr[s] + atomicAdd(&cursor[s], 1);
    csr_p[pos] = att_exp[e];
    csr_d[pos] = dstI[e];
}

// ---------------------------------------------------------------------------
// K3: per-node gather-aggregate: agg[n] = sum(p*h[dst]) / sum(p)
// ---------------------------------------------------------------------------
__global__ __launch_bounds__(256) void k_agg(
    const int* __restrict__ rowptr, const float* __restrict__ csr_p,
    const int* __restrict__ csr_d, const ushort* __restrict__ Hb,
    float* __restrict__ agg)
{
    __shared__ float4 red[8][32];
    __shared__ float sred[8];
    const int tid = threadIdx.x, tc = tid & 31, slot = tid >> 5;
    const int n = blockIdx.x;
    const int beg = rowptr[n], end = rowptr[n + 1];

    float4 v = {0.f, 0.f, 0.f, 0.f};
    float sp = 0.f;
    for (int j = beg + slot; j < end; j += 8) {
        const float p = csr_p[j];
        const int d = csr_d[j];
        const ushort4 hv = *reinterpret_cast<const ushort4*>(Hb + (size_t)d * 128 + tc * 4);
        v.x = fmaf(p, bf2f(hv.x), v.x);
        v.y = fmaf(p, bf2f(hv.y), v.y);
        v.z = fmaf(p, bf2f(hv.z), v.z);
        v.w = fmaf(p, bf2f(hv.w), v.w);
        sp += p;
    }
    red[slot][tc] = v;
    if (tc == 0) sred[slot] = sp;
    __syncthreads();
    if (tid < 32) {
        float4 a = red[0][tid];
        float S = sred[0];
#pragma unroll
        for (int s = 1; s < 8; ++s) {
            const float4 b = red[s][tid];
            a.x += b.x; a.y += b.y; a.z += b.z; a.w += b.w;
            S += sred[s];
        }
        const float inv = (end > beg) ? 1.f / S : 0.f;
        const float4 o = {a.x * inv, a.y * inv, a.z * inv, a.w * inv};
        reinterpret_cast<float4*>(agg)[(size_t)n * 32 + tid] = o;
    }
}

// ---------------------------------------------------------------------------
// K4: o = agg @ W_out + b_out ; LayerNorm ; ReLU
// ---------------------------------------------------------------------------
__global__ __launch_bounds__(512) void k_out_ln(
    const float* __restrict__ AGG, const float* __restrict__ W,
    const float* __restrict__ b, const float* __restrict__ gamma,
    const float* __restrict__ beta, float* __restrict__ OUT)
{
    __shared__ float xs[4 * 128];
    __shared__ float red[8][2];
    const int tid = threadIdx.x;
    const int col = tid & 127, g = tid >> 7;
    const int node = blockIdx.x * 4 + g;

    xs[tid] = AGG[(size_t)node * 128 + col];
    __syncthreads();

    float acc = b[col];
    for (int k = 0; k < 128; ++k)
        acc = fmaf(xs[g * 128 + k], W[k * 128 + col], acc);

    float s1 = acc, s2 = acc * acc;
#pragma unroll
    for (int m = 1; m < 64; m <<= 1) {
        s1 += __shfl_xor(s1, m, 64);
        s2 += __shfl_xor(s2, m, 64);
    }
    const int wid = tid >> 6;
    if ((tid & 63) == 0) { red[wid][0] = s1; red[wid][1] = s2; }
    __syncthreads();

    const float S1 = red[2 * g][0] + red[2 * g + 1][0];
    const float S2 = red[2 * g][1] + red[2 * g + 1][1];
    const float mu = S1 * (1.f / 128.f);
    const float var = S2 * (1.f / 128.f) - mu * mu;
    const float rr = rsqrtf(var + 1e-5f);
    const float o = (acc - mu) * rr * gamma[col] + beta[col];
    OUT[(size_t)node * 128 + col] = o > 0.f ? o : 0.f;
}

// ---------------------------------------------------------------------------
extern "C" void kernel_launch(void* const* d_in, const int* in_sizes, int n_in,
                              void* d_out, int out_size, void* d_ws, size_t ws_size,
                              hipStream_t stream)
{
    const float* node_features = (const float*)d_in[0];
    const int*   edge_index    = (const int*)d_in[1];
    const float* edge_features = (const float*)d_in[2];
    const float* W_node  = (const float*)d_in[3];
    const float* b_node  = (const float*)d_in[4];
    const float* W_edge  = (const float*)d_in[5];
    const float* b_edge  = (const float*)d_in[6];
    const float* W_att1  = (const float*)d_in[7];
    const float* b_att1  = (const float*)d_in[8];
    const float* W_att2  = (const float*)d_in[9];
    const float* b_att2  = (const float*)d_in[10];
    const float* W_out   = (const float*)d_in[11];
    const float* b_out   = (const float*)d_in[12];
    const float* ln_gamma = (const float*)d_in[13];
    const float* ln_beta  = (const float*)d_in[14];
    float* out = (float*)d_out;

    // workspace layout (byte offsets, 16B-aligned)
    char* ws = (char*)d_ws;
    ushort* hb      = (ushort*)(ws);                   // 10,240,000 B
    float*  att_exp = (float*)(ws + 10240000);         //  2,560,000 B
    float*  csr_p   = (float*)(ws + 12800000);         //  2,560,000 B
    int*    csr_d   = (int*)(ws + 15360000);           //  2,560,000 B
    int*    rowptr  = (int*)(ws + 17920000);           //    160,004 B
    int*    cnt     = (int*)(ws + 18080016);           //    160,000 B
    int*    cursor  = (int*)(ws + 18240016);           //    160,000 B (contiguous after cnt)
    float*  agg     = (float*)(ws + 18400016);         // 20,480,000 B
    float*  Wc      = (float*)(ws + 38880016);         //     32,768 B
    float*  b_eff   = (float*)(ws + 38912784);         //        512 B
    ushort* pack    = (ushort*)(ws + 38913296);        //     81,920 B

    const int* srcI = edge_index;
    const int* dstI = edge_index + N_EDGES;

    // zero histogram + fill cursors (contiguous)
    hipMemsetAsync(cnt, 0, 320000, stream);

    k_node_gemm<<<N_NODES / 16, 256, 0, stream>>>(node_features, W_node, b_node, hb);
    k_wcomb<<<33, 256, 0, stream>>>(W_edge, W_att1, b_att1, b_edge, Wc, b_eff);
    k_pack<<<160, 256, 0, stream>>>(W_att1, Wc, pack);
    k_hist<<<N_EDGES / 256, 256, 0, stream>>>(srcI, cnt);
    k_scan<<<1, 1024, 0, stream>>>(cnt, rowptr);
    k_edge_att_mfma<<<N_EDGES / 256, 512, 0, stream>>>(srcI, dstI, edge_features, hb,
                                                       pack, b_eff, W_att2, b_att2,
                                                       att_exp);
    k_fill<<<N_EDGES / 256, 256, 0, stream>>>(srcI, dstI, att_exp, rowptr,
                                              cursor, csr_p, csr_d);
    k_agg<<<N_NODES, 256, 0, stream>>>(rowptr, csr_p, csr_d, hb, agg);
    k_out_ln<<<N_NODES / 4, 512, 0, stream>>>(agg, W_out, b_out, ln_gamma, ln_beta, out);
}

// Round 10
// 400.242 us; speedup vs baseline: 5.8351x; 1.0477x over previous
//
#include <hip/hip_runtime.h>
#include <math.h>

#define N_NODES 40000
#define N_EDGES 640000
#define IN_DIM 128
#define EDGE_DIM 64
#define HID 128

typedef __attribute__((ext_vector_type(8))) short bf16x8;
typedef __attribute__((ext_vector_type(4))) float f32x4;

__device__ __forceinline__ ushort f2bf(float f) {
    unsigned int x = __float_as_uint(f);
    x += 0x7fffu + ((x >> 16) & 1u);
    return (ushort)(x >> 16);
}
__device__ __forceinline__ float bf2f(ushort u) {
    return __uint_as_float(((unsigned int)u) << 16);
}
// tanh(x) = 1 - 2/(e^{2x}+1); e^{2x}=inf -> 1, e^{2x}=0 -> -1 (no NaN)
__device__ __forceinline__ float tanh_fast(float x) {
    return 1.f - __fdividef(2.f, __expf(2.f * x) + 1.f);
}

// ---------------------------------------------------------------------------
// K1: h = node_features @ W_node + b_node ; bf16 output only.
// ---------------------------------------------------------------------------
__global__ __launch_bounds__(256) void k_node_gemm(
    const float* __restrict__ X, const float* __restrict__ W,
    const float* __restrict__ b, ushort* __restrict__ Hb)
{
    __shared__ float xs[16 * 128];
    const int tid = threadIdx.x;
    const int base = blockIdx.x * 16;

    const float4* Xg = reinterpret_cast<const float4*>(X + (size_t)base * 128);
    float4* xs4 = reinterpret_cast<float4*>(xs);
#pragma unroll
    for (int i = 0; i < 2; ++i) xs4[tid + 256 * i] = Xg[tid + 256 * i];
    __syncthreads();

    const int col = tid & 127, g = tid >> 7;
    float acc[8];
#pragma unroll
    for (int i = 0; i < 8; ++i) acc[i] = 0.f;

    for (int k = 0; k < 128; ++k) {
        const float w = W[k * 128 + col];
#pragma unroll
        for (int i = 0; i < 8; ++i) acc[i] = fmaf(xs[(g + 2 * i) * 128 + k], w, acc[i]);
    }
    const float bb = b[col];
#pragma unroll
    for (int i = 0; i < 8; ++i)
        Hb[(size_t)(base + g + 2 * i) * 128 + col] = f2bf(acc[i] + bb);
}

// ---------------------------------------------------------------------------
// Setup A: W_comb = W_edge @ W1[256:384]; b_eff = b_att1 + b_edge @ W1he
// ---------------------------------------------------------------------------
__global__ __launch_bounds__(256) void k_wcomb(
    const float* __restrict__ W_edge, const float* __restrict__ W1,
    const float* __restrict__ b_att1, const float* __restrict__ b_edge,
    float* __restrict__ Wc, float* __restrict__ b_eff)
{
    const float* W1he = W1 + 256 * 128;
    if (blockIdx.x == 32) {
        const int n = threadIdx.x;
        if (n < 128) {
            float s = b_att1[n];
            for (int k = 0; k < 128; ++k) s = fmaf(b_edge[k], W1he[k * 128 + n], s);
            b_eff[n] = s;
        }
        return;
    }
    const int idx = blockIdx.x * 256 + threadIdx.x;
    const int row = idx >> 7, n = idx & 127;
    float s = 0.f;
    for (int k = 0; k < 128; ++k) s = fmaf(W_edge[row * 128 + k], W1he[k * 128 + n], s);
    Wc[idx] = s;
}

// ---------------------------------------------------------------------------
// Setup B: pack B-operand fragments in MFMA lane order, bf16.
// pack[k0][nt][lane] : bf16x8 per (k0,nt,lane); k = k0*32+(lane>>4)*8+j, n = nt*16+(lane&15)
// ---------------------------------------------------------------------------
__global__ __launch_bounds__(256) void k_pack(
    const float* __restrict__ W1, const float* __restrict__ Wc,
    ushort* __restrict__ pack)
{
    const int idx = blockIdx.x * 256 + threadIdx.x;   // 0..40959
    const int j = idx & 7, lane = (idx >> 3) & 63, nt = (idx >> 9) & 7, k0 = idx >> 12;
    const int k = k0 * 32 + (lane >> 4) * 8 + j;
    const int n = nt * 16 + (lane & 15);
    const float v = (k < 256) ? W1[k * 128 + n] : Wc[(k - 256) * 128 + n];
    pack[idx] = f2bf(v);
}

// ---------------------------------------------------------------------------
// K2: per-edge attention p = exp(tanh(cat@W1 + b)@W2 + b2) via MFMA.
// 512 threads = 8 waves; wave = 32 edges (two 16-row m-tiles sharing B frags).
// Full B pack (80 KB) staged in LDS once per block -> B reads are ds_read_b128.
// min-waves/EU = 2 (NOT 4): VGPR cap 256 so the 64 acc regs stay in registers;
// LDS (80 KB) already limits occupancy to 2 blocks/CU, so nothing is lost.
// ---------------------------------------------------------------------------
__global__ __launch_bounds__(512, 2) void k_edge_att_mfma(
    const int* __restrict__ srcI, const int* __restrict__ dstI,
    const float* __restrict__ EF, const ushort* __restrict__ Hb,
    const ushort* __restrict__ Bpack, const float* __restrict__ b_eff,
    const float* __restrict__ W2, const float* __restrict__ b2,
    float* __restrict__ att_exp)
{
    __shared__ ushort bsh[40960];   // 80 KB: full packed B

    const int tid = threadIdx.x;

    // cooperative stage: 5120 x 16B frags / 512 threads = 10 each
    {
        const bf16x8* Bg = reinterpret_cast<const bf16x8*>(Bpack);
        bf16x8* Bs = reinterpret_cast<bf16x8*>(bsh);
#pragma unroll
        for (int i = 0; i < 10; ++i) Bs[tid + 512 * i] = Bg[tid + 512 * i];
    }
    __syncthreads();
    const bf16x8* Bp = reinterpret_cast<const bf16x8*>(bsh);

    const int wave = tid >> 6, lane = tid & 63;
    const int r = lane & 15, g = lane >> 4;
    const int ebase = blockIdx.x * 256 + wave * 32;
    const int e0 = ebase + r, e1 = ebase + 16 + r;

    const int s0 = srcI[e0], d0 = dstI[e0];
    const int s1 = srcI[e1], d1 = dstI[e1];
    const ushort* rowS0 = Hb + (size_t)s0 * 128 + g * 8;
    const ushort* rowD0 = Hb + (size_t)d0 * 128 + g * 8;
    const ushort* rowS1 = Hb + (size_t)s1 * 128 + g * 8;
    const ushort* rowD1 = Hb + (size_t)d1 * 128 + g * 8;
    const float*  rowE0 = EF + (size_t)e0 * 64 + g * 8;
    const float*  rowE1 = EF + (size_t)e1 * 64 + g * 8;

    f32x4 acc0[8], acc1[8];
#pragma unroll
    for (int nt = 0; nt < 8; ++nt) {
        const float bv = b_eff[nt * 16 + r];
        acc0[nt] = (f32x4){bv, bv, bv, bv};
        acc1[nt] = (f32x4){bv, bv, bv, bv};
    }

    // chunk 1: h_src (k0 = 0..3)
#pragma unroll
    for (int k0 = 0; k0 < 4; ++k0) {
        const bf16x8 a0 = *reinterpret_cast<const bf16x8*>(rowS0 + k0 * 32);
        const bf16x8 a1 = *reinterpret_cast<const bf16x8*>(rowS1 + k0 * 32);
#pragma unroll
        for (int nt = 0; nt < 8; ++nt) {
            const bf16x8 bfrag = Bp[(k0 * 8 + nt) * 64 + lane];
            acc0[nt] = __builtin_amdgcn_mfma_f32_16x16x32_bf16(a0, bfrag, acc0[nt], 0, 0, 0);
            acc1[nt] = __builtin_amdgcn_mfma_f32_16x16x32_bf16(a1, bfrag, acc1[nt], 0, 0, 0);
        }
    }
    // chunk 2: h_dst (k0 = 4..7)
#pragma unroll
    for (int k0 = 0; k0 < 4; ++k0) {
        const bf16x8 a0 = *reinterpret_cast<const bf16x8*>(rowD0 + k0 * 32);
        const bf16x8 a1 = *reinterpret_cast<const bf16x8*>(rowD1 + k0 * 32);
#pragma unroll
        for (int nt = 0; nt < 8; ++nt) {
            const bf16x8 bfrag = Bp[((k0 + 4) * 8 + nt) * 64 + lane];
            acc0[nt] = __builtin_amdgcn_mfma_f32_16x16x32_bf16(a0, bfrag, acc0[nt], 0, 0, 0);
            acc1[nt] = __builtin_amdgcn_mfma_f32_16x16x32_bf16(a1, bfrag, acc1[nt], 0, 0, 0);
        }
    }
    // chunk 3: EF fp32 -> bf16 on the fly (k0 = 8..9)
#pragma unroll
    for (int k0 = 0; k0 < 2; ++k0) {
        const float4 p0 = *reinterpret_cast<const float4*>(rowE0 + k0 * 32);
        const float4 p1 = *reinterpret_cast<const float4*>(rowE0 + k0 * 32 + 4);
        const float4 q0 = *reinterpret_cast<const float4*>(rowE1 + k0 * 32);
        const float4 q1 = *reinterpret_cast<const float4*>(rowE1 + k0 * 32 + 4);
        bf16x8 a0, a1;
        a0[0] = (short)f2bf(p0.x); a0[1] = (short)f2bf(p0.y);
        a0[2] = (short)f2bf(p0.z); a0[3] = (short)f2bf(p0.w);
        a0[4] = (short)f2bf(p1.x); a0[5] = (short)f2bf(p1.y);
        a0[6] = (short)f2bf(p1.z); a0[7] = (short)f2bf(p1.w);
        a1[0] = (short)f2bf(q0.x); a1[1] = (short)f2bf(q0.y);
        a1[2] = (short)f2bf(q0.z); a1[3] = (short)f2bf(q0.w);
        a1[4] = (short)f2bf(q1.x); a1[5] = (short)f2bf(q1.y);
        a1[6] = (short)f2bf(q1.z); a1[7] = (short)f2bf(q1.w);
#pragma unroll
        for (int nt = 0; nt < 8; ++nt) {
            const bf16x8 bfrag = Bp[((k0 + 8) * 8 + nt) * 64 + lane];
            acc0[nt] = __builtin_amdgcn_mfma_f32_16x16x32_bf16(a0, bfrag, acc0[nt], 0, 0, 0);
            acc1[nt] = __builtin_amdgcn_mfma_f32_16x16x32_bf16(a1, bfrag, acc1[nt], 0, 0, 0);
        }
    }

    // epilogue: a = tanh(z)@W2 ; reduce over col groups ; p = exp(a + b2)
    float part0[4] = {0.f, 0.f, 0.f, 0.f};
    float part1[4] = {0.f, 0.f, 0.f, 0.f};
#pragma unroll
    for (int nt = 0; nt < 8; ++nt) {
        const float w2v = W2[nt * 16 + r];
#pragma unroll
        for (int q = 0; q < 4; ++q) {
            part0[q] = fmaf(tanh_fast(acc0[nt][q]), w2v, part0[q]);
            part1[q] = fmaf(tanh_fast(acc1[nt][q]), w2v, part1[q]);
        }
    }
#pragma unroll
    for (int m = 1; m <= 8; m <<= 1) {
#pragma unroll
        for (int q = 0; q < 4; ++q) {
            part0[q] += __shfl_xor(part0[q], m, 64);
            part1[q] += __shfl_xor(part1[q], m, 64);
        }
    }
    if (r == 0) {
        const float bb2 = b2[0];
#pragma unroll
        for (int q = 0; q < 4; ++q) {
            att_exp[ebase + g * 4 + q]      = __expf(part0[q] + bb2);
            att_exp[ebase + 16 + g * 4 + q] = __expf(part1[q] + bb2);
        }
    }
}

// ---------------------------------------------------------------------------
// CSR build: histogram -> single-block scan -> fill (p,dst) in segment order
// ---------------------------------------------------------------------------
__global__ __launch_bounds__(256) void k_hist(
    const int* __restrict__ srcI, int* __restrict__ cnt)
{
    const int e = blockIdx.x * 256 + threadIdx.x;
    atomicAdd(&cnt[srcI[e]], 1);
}

__global__ __launch_bounds__(1024) void k_scan(
    const int* __restrict__ cnt, int* __restrict__ rowptr)
{
    __shared__ int wsum[16];
    __shared__ int carry;
    const int tid = threadIdx.x, lane = tid & 63, wid = tid >> 6;
    if (tid == 0) { carry = 0; rowptr[0] = 0; }
    __syncthreads();
    for (int base = 0; base < N_NODES; base += 1024) {
        const int i = base + tid;
        int v = (i < N_NODES) ? cnt[i] : 0;
#pragma unroll
        for (int d = 1; d < 64; d <<= 1) {
            const int t = __shfl_up(v, d, 64);
            if (lane >= d) v += t;
        }
        if (lane == 63) wsum[wid] = v;
        __syncthreads();
        if (wid == 0 && lane < 16) {
            int w = wsum[lane];
#pragma unroll
            for (int d = 1; d < 16; d <<= 1) {
                const int t = __shfl_up(w, d, 16);
                if ((lane & 15) >= d) w += t;
            }
            wsum[lane] = w;
        }
        __syncthreads();
        const int off = (wid == 0) ? 0 : wsum[wid - 1];
        const int res = carry + off + v;
        if (i < N_NODES) rowptr[i + 1] = res;
        const int total = wsum[15];
        __syncthreads();
        if (tid == 0) carry += total;
        __syncthreads();
    }
}

__global__ __launch_bounds__(256) void k_fill(
    const int* __restrict__ srcI, const int* __restrict__ dstI,
    const float* __restrict__ att_exp, const int* __restrict__ rowptr,
    int* __restrict__ cursor, float* __restrict__ csr_p, int* __restrict__ csr_d)
{
    const int e = blockIdx.x * 256 + threadIdx.x;
    const int s = srcI[e];
    const int pos = rowptr[s] + atomicAdd(&cursor[s], 1);
    csr_p[pos] = att_exp[e];
    csr_d[pos] = dstI[e];
}

// ---------------------------------------------------------------------------
// K3: per-node gather-aggregate: agg[n] = sum(p*h[dst]) / sum(p)
// ---------------------------------------------------------------------------
__global__ __launch_bounds__(256) void k_agg(
    const int* __restrict__ rowptr, const float* __restrict__ csr_p,
    const int* __restrict__ csr_d, const ushort* __restrict__ Hb,
    float* __restrict__ agg)
{
    __shared__ float4 red[8][32];
    __shared__ float sred[8];
    const int tid = threadIdx.x, tc = tid & 31, slot = tid >> 5;
    const int n = blockIdx.x;
    const int beg = rowptr[n], end = rowptr[n + 1];

    float4 v = {0.f, 0.f, 0.f, 0.f};
    float sp = 0.f;
    for (int j = beg + slot; j < end; j += 8) {
        const float p = csr_p[j];
        const int d = csr_d[j];
        const ushort4 hv = *reinterpret_cast<const ushort4*>(Hb + (size_t)d * 128 + tc * 4);
        v.x = fmaf(p, bf2f(hv.x), v.x);
        v.y = fmaf(p, bf2f(hv.y), v.y);
        v.z = fmaf(p, bf2f(hv.z), v.z);
        v.w = fmaf(p, bf2f(hv.w), v.w);
        sp += p;
    }
    red[slot][tc] = v;
    if (tc == 0) sred[slot] = sp;
    __syncthreads();
    if (tid < 32) {
        float4 a = red[0][tid];
        float S = sred[0];
#pragma unroll
        for (int s = 1; s < 8; ++s) {
            const float4 b = red[s][tid];
            a.x += b.x; a.y += b.y; a.z += b.z; a.w += b.w;
            S += sred[s];
        }
        const float inv = (end > beg) ? 1.f / S : 0.f;
        const float4 o = {a.x * inv, a.y * inv, a.z * inv, a.w * inv};
        reinterpret_cast<float4*>(agg)[(size_t)n * 32 + tid] = o;
    }
}

// ---------------------------------------------------------------------------
// K4: o = agg @ W_out + b_out ; LayerNorm ; ReLU
// ---------------------------------------------------------------------------
__global__ __launch_bounds__(512) void k_out_ln(
    const float* __restrict__ AGG, const float* __restrict__ W,
    const float* __restrict__ b, const float* __restrict__ gamma,
    const float* __restrict__ beta, float* __restrict__ OUT)
{
    __shared__ float xs[4 * 128];
    __shared__ float red[8][2];
    const int tid = threadIdx.x;
    const int col = tid & 127, g = tid >> 7;
    const int node = blockIdx.x * 4 + g;

    xs[tid] = AGG[(size_t)node * 128 + col];
    __syncthreads();

    float acc = b[col];
    for (int k = 0; k < 128; ++k)
        acc = fmaf(xs[g * 128 + k], W[k * 128 + col], acc);

    float s1 = acc, s2 = acc * acc;
#pragma unroll
    for (int m = 1; m < 64; m <<= 1) {
        s1 += __shfl_xor(s1, m, 64);
        s2 += __shfl_xor(s2, m, 64);
    }
    const int wid = tid >> 6;
    if ((tid & 63) == 0) { red[wid][0] = s1; red[wid][1] = s2; }
    __syncthreads();

    const float S1 = red[2 * g][0] + red[2 * g + 1][0];
    const float S2 = red[2 * g][1] + red[2 * g + 1][1];
    const float mu = S1 * (1.f / 128.f);
    const float var = S2 * (1.f / 128.f) - mu * mu;
    const float rr = rsqrtf(var + 1e-5f);
    const float o = (acc - mu) * rr * gamma[col] + beta[col];
    OUT[(size_t)node * 128 + col] = o > 0.f ? o : 0.f;
}

// ---------------------------------------------------------------------------
extern "C" void kernel_launch(void* const* d_in, const int* in_sizes, int n_in,
                              void* d_out, int out_size, void* d_ws, size_t ws_size,
                              hipStream_t stream)
{
    const float* node_features = (const float*)d_in[0];
    const int*   edge_index    = (const int*)d_in[1];
    const float* edge_features = (const float*)d_in[2];
    const float* W_node  = (const float*)d_in[3];
    const float* b_node  = (const float*)d_in[4];
    const float* W_edge  = (const float*)d_in[5];
    const float* b_edge  = (const float*)d_in[6];
    const float* W_att1  = (const float*)d_in[7];
    const float* b_att1  = (const float*)d_in[8];
    const float* W_att2  = (const float*)d_in[9];
    const float* b_att2  = (const float*)d_in[10];
    const float* W_out   = (const float*)d_in[11];
    const float* b_out   = (const float*)d_in[12];
    const float* ln_gamma = (const float*)d_in[13];
    const float* ln_beta  = (const float*)d_in[14];
    float* out = (float*)d_out;

    // workspace layout (byte offsets, 16B-aligned)
    char* ws = (char*)d_ws;
    ushort* hb      = (ushort*)(ws);                   // 10,240,000 B
    float*  att_exp = (float*)(ws + 10240000);         //  2,560,000 B
    float*  csr_p   = (float*)(ws + 12800000);         //  2,560,000 B
    int*    csr_d   = (int*)(ws + 15360000);           //  2,560,000 B
    int*    rowptr  = (int*)(ws + 17920000);           //    160,004 B
    int*    cnt     = (int*)(ws + 18080016);           //    160,000 B
    int*    cursor  = (int*)(ws + 18240016);           //    160,000 B (contiguous after cnt)
    float*  agg     = (float*)(ws + 18400016);         // 20,480,000 B
    float*  Wc      = (float*)(ws + 38880016);         //     32,768 B
    float*  b_eff   = (float*)(ws + 38912784);         //        512 B
    ushort* pack    = (ushort*)(ws + 38913296);        //     81,920 B

    const int* srcI = edge_index;
    const int* dstI = edge_index + N_EDGES;

    // zero histogram + fill cursors (contiguous)
    hipMemsetAsync(cnt, 0, 320000, stream);

    k_node_gemm<<<N_NODES / 16, 256, 0, stream>>>(node_features, W_node, b_node, hb);
    k_wcomb<<<33, 256, 0, stream>>>(W_edge, W_att1, b_att1, b_edge, Wc, b_eff);
    k_pack<<<160, 256, 0, stream>>>(W_att1, Wc, pack);
    k_hist<<<N_EDGES / 256, 256, 0, stream>>>(srcI, cnt);
    k_scan<<<1, 1024, 0, stream>>>(cnt, rowptr);
    k_edge_att_mfma<<<N_EDGES / 256, 512, 0, stream>>>(srcI, dstI, edge_features, hb,
                                                       pack, b_eff, W_att2, b_att2,
                                                       att_exp);
    k_fill<<<N_EDGES / 256, 256, 0, stream>>>(srcI, dstI, att_exp, rowptr,
                                              cursor, csr_p, csr_d);
    k_agg<<<N_NODES, 256, 0, stream>>>(rowptr, csr_p, csr_d, hb, agg);
    k_out_ln<<<N_NODES / 4, 512, 0, stream>>>(agg, W_out, b_out, ln_gamma, ln_beta, out);
}

// Round 11
// 377.696 us; speedup vs baseline: 6.1835x; 1.0597x over previous
//
#include <hip/hip_runtime.h>
#include <math.h>

#define N_NODES 40000
#define N_EDGES 640000
#define IN_DIM 128
#define EDGE_DIM 64
#define HID 128

typedef __attribute__((ext_vector_type(8))) short bf16x8;
typedef __attribute__((ext_vector_type(4))) float f32x4;

__device__ __forceinline__ ushort f2bf(float f) {
    unsigned int x = __float_as_uint(f);
    x += 0x7fffu + ((x >> 16) & 1u);
    return (ushort)(x >> 16);
}
__device__ __forceinline__ float bf2f(ushort u) {
    return __uint_as_float(((unsigned int)u) << 16);
}
// tanh(x) = 1 - 2/(e^{2x}+1); e^{2x}=inf -> 1, e^{2x}=0 -> -1 (no NaN)
__device__ __forceinline__ float tanh_fast(float x) {
    return 1.f - __fdividef(2.f, __expf(2.f * x) + 1.f);
}

// ---------------------------------------------------------------------------
// K1: h = node_features @ W_node + b_node ; bf16 output only.
// ---------------------------------------------------------------------------
__global__ __launch_bounds__(256) void k_node_gemm(
    const float* __restrict__ X, const float* __restrict__ W,
    const float* __restrict__ b, ushort* __restrict__ Hb)
{
    __shared__ float xs[16 * 128];
    const int tid = threadIdx.x;
    const int base = blockIdx.x * 16;

    const float4* Xg = reinterpret_cast<const float4*>(X + (size_t)base * 128);
    float4* xs4 = reinterpret_cast<float4*>(xs);
#pragma unroll
    for (int i = 0; i < 2; ++i) xs4[tid + 256 * i] = Xg[tid + 256 * i];
    __syncthreads();

    const int col = tid & 127, g = tid >> 7;
    float acc[8];
#pragma unroll
    for (int i = 0; i < 8; ++i) acc[i] = 0.f;

    for (int k = 0; k < 128; ++k) {
        const float w = W[k * 128 + col];
#pragma unroll
        for (int i = 0; i < 8; ++i) acc[i] = fmaf(xs[(g + 2 * i) * 128 + k], w, acc[i]);
    }
    const float bb = b[col];
#pragma unroll
    for (int i = 0; i < 8; ++i)
        Hb[(size_t)(base + g + 2 * i) * 128 + col] = f2bf(acc[i] + bb);
}

// ---------------------------------------------------------------------------
// Setup A: W_comb = W_edge @ W1[256:384]; b_eff = b_att1 + b_edge @ W1he
// ---------------------------------------------------------------------------
__global__ __launch_bounds__(256) void k_wcomb(
    const float* __restrict__ W_edge, const float* __restrict__ W1,
    const float* __restrict__ b_att1, const float* __restrict__ b_edge,
    float* __restrict__ Wc, float* __restrict__ b_eff)
{
    const float* W1he = W1 + 256 * 128;
    if (blockIdx.x == 32) {
        const int n = threadIdx.x;
        if (n < 128) {
            float s = b_att1[n];
            for (int k = 0; k < 128; ++k) s = fmaf(b_edge[k], W1he[k * 128 + n], s);
            b_eff[n] = s;
        }
        return;
    }
    const int idx = blockIdx.x * 256 + threadIdx.x;
    const int row = idx >> 7, n = idx & 127;
    float s = 0.f;
    for (int k = 0; k < 128; ++k) s = fmaf(W_edge[row * 128 + k], W1he[k * 128 + n], s);
    Wc[idx] = s;
}

// ---------------------------------------------------------------------------
// Setup B: pack B-operand fragments in MFMA lane order, bf16.
// pack[k0][nt][lane] : bf16x8 per (k0,nt,lane); k = k0*32+(lane>>4)*8+j, n = nt*16+(lane&15)
// ---------------------------------------------------------------------------
__global__ __launch_bounds__(256) void k_pack(
    const float* __restrict__ W1, const float* __restrict__ Wc,
    ushort* __restrict__ pack)
{
    const int idx = blockIdx.x * 256 + threadIdx.x;   // 0..40959
    const int j = idx & 7, lane = (idx >> 3) & 63, nt = (idx >> 9) & 7, k0 = idx >> 12;
    const int k = k0 * 32 + (lane >> 4) * 8 + j;
    const int n = nt * 16 + (lane & 15);
    const float v = (k < 256) ? W1[k * 128 + n] : Wc[(k - 256) * 128 + n];
    pack[idx] = f2bf(v);
}

// ---------------------------------------------------------------------------
// K2: per-edge attention p = exp(tanh(cat@W1 + b)@W2 + b2) via MFMA.
// 512 threads = 8 waves; wave = 32 edges (two 16-row m-tiles sharing B frags).
// B pack for k0=0..7 (64 KB) in LDS -> 2 blocks/CU resident (128 KB LDS);
// k0=8..9 B frags (16 KB) read from global (L2-hot, reused 20000x).
// ---------------------------------------------------------------------------
__global__ __launch_bounds__(512, 2) void k_edge_att_mfma(
    const int* __restrict__ srcI, const int* __restrict__ dstI,
    const float* __restrict__ EF, const ushort* __restrict__ Hb,
    const ushort* __restrict__ Bpack, const float* __restrict__ b_eff,
    const float* __restrict__ W2, const float* __restrict__ b2,
    float* __restrict__ att_exp)
{
    __shared__ ushort bsh[32768];   // 64 KB: B pack for k0 = 0..7

    const int tid = threadIdx.x;

    // cooperative stage: 4096 x 16B frags / 512 threads = 8 each
    {
        const bf16x8* Bg = reinterpret_cast<const bf16x8*>(Bpack);
        bf16x8* Bs = reinterpret_cast<bf16x8*>(bsh);
#pragma unroll
        for (int i = 0; i < 8; ++i) Bs[tid + 512 * i] = Bg[tid + 512 * i];
    }
    __syncthreads();
    const bf16x8* Bp = reinterpret_cast<const bf16x8*>(bsh);
    const bf16x8* BpG = reinterpret_cast<const bf16x8*>(Bpack);  // global, k0=8..9

    const int wave = tid >> 6, lane = tid & 63;
    const int r = lane & 15, g = lane >> 4;
    const int ebase = blockIdx.x * 256 + wave * 32;
    const int e0 = ebase + r, e1 = ebase + 16 + r;

    const int s0 = srcI[e0], d0 = dstI[e0];
    const int s1 = srcI[e1], d1 = dstI[e1];
    const ushort* rowS0 = Hb + (size_t)s0 * 128 + g * 8;
    const ushort* rowD0 = Hb + (size_t)d0 * 128 + g * 8;
    const ushort* rowS1 = Hb + (size_t)s1 * 128 + g * 8;
    const ushort* rowD1 = Hb + (size_t)d1 * 128 + g * 8;
    const float*  rowE0 = EF + (size_t)e0 * 64 + g * 8;
    const float*  rowE1 = EF + (size_t)e1 * 64 + g * 8;

    f32x4 acc0[8], acc1[8];
#pragma unroll
    for (int nt = 0; nt < 8; ++nt) {
        const float bv = b_eff[nt * 16 + r];
        acc0[nt] = (f32x4){bv, bv, bv, bv};
        acc1[nt] = (f32x4){bv, bv, bv, bv};
    }

    // chunk 1: h_src (k0 = 0..3), B from LDS
#pragma unroll
    for (int k0 = 0; k0 < 4; ++k0) {
        const bf16x8 a0 = *reinterpret_cast<const bf16x8*>(rowS0 + k0 * 32);
        const bf16x8 a1 = *reinterpret_cast<const bf16x8*>(rowS1 + k0 * 32);
#pragma unroll
        for (int nt = 0; nt < 8; ++nt) {
            const bf16x8 bfrag = Bp[(k0 * 8 + nt) * 64 + lane];
            acc0[nt] = __builtin_amdgcn_mfma_f32_16x16x32_bf16(a0, bfrag, acc0[nt], 0, 0, 0);
            acc1[nt] = __builtin_amdgcn_mfma_f32_16x16x32_bf16(a1, bfrag, acc1[nt], 0, 0, 0);
        }
    }
    // chunk 2: h_dst (k0 = 4..7), B from LDS
#pragma unroll
    for (int k0 = 0; k0 < 4; ++k0) {
        const bf16x8 a0 = *reinterpret_cast<const bf16x8*>(rowD0 + k0 * 32);
        const bf16x8 a1 = *reinterpret_cast<const bf16x8*>(rowD1 + k0 * 32);
#pragma unroll
        for (int nt = 0; nt < 8; ++nt) {
            const bf16x8 bfrag = Bp[((k0 + 4) * 8 + nt) * 64 + lane];
            acc0[nt] = __builtin_amdgcn_mfma_f32_16x16x32_bf16(a0, bfrag, acc0[nt], 0, 0, 0);
            acc1[nt] = __builtin_amdgcn_mfma_f32_16x16x32_bf16(a1, bfrag, acc1[nt], 0, 0, 0);
        }
    }
    // chunk 3: EF fp32 -> bf16 on the fly (k0 = 8..9), B from global (L2)
#pragma unroll
    for (int k0 = 0; k0 < 2; ++k0) {
        const float4 p0 = *reinterpret_cast<const float4*>(rowE0 + k0 * 32);
        const float4 p1 = *reinterpret_cast<const float4*>(rowE0 + k0 * 32 + 4);
        const float4 q0 = *reinterpret_cast<const float4*>(rowE1 + k0 * 32);
        const float4 q1 = *reinterpret_cast<const float4*>(rowE1 + k0 * 32 + 4);
        bf16x8 a0, a1;
        a0[0] = (short)f2bf(p0.x); a0[1] = (short)f2bf(p0.y);
        a0[2] = (short)f2bf(p0.z); a0[3] = (short)f2bf(p0.w);
        a0[4] = (short)f2bf(p1.x); a0[5] = (short)f2bf(p1.y);
        a0[6] = (short)f2bf(p1.z); a0[7] = (short)f2bf(p1.w);
        a1[0] = (short)f2bf(q0.x); a1[1] = (short)f2bf(q0.y);
        a1[2] = (short)f2bf(q0.z); a1[3] = (short)f2bf(q0.w);
        a1[4] = (short)f2bf(q1.x); a1[5] = (short)f2bf(q1.y);
        a1[6] = (short)f2bf(q1.z); a1[7] = (short)f2bf(q1.w);
#pragma unroll
        for (int nt = 0; nt < 8; ++nt) {
            const bf16x8 bfrag = BpG[((k0 + 8) * 8 + nt) * 64 + lane];
            acc0[nt] = __builtin_amdgcn_mfma_f32_16x16x32_bf16(a0, bfrag, acc0[nt], 0, 0, 0);
            acc1[nt] = __builtin_amdgcn_mfma_f32_16x16x32_bf16(a1, bfrag, acc1[nt], 0, 0, 0);
        }
    }

    // epilogue: a = tanh(z)@W2 ; reduce over col groups ; p = exp(a + b2)
    float part0[4] = {0.f, 0.f, 0.f, 0.f};
    float part1[4] = {0.f, 0.f, 0.f, 0.f};
#pragma unroll
    for (int nt = 0; nt < 8; ++nt) {
        const float w2v = W2[nt * 16 + r];
#pragma unroll
        for (int q = 0; q < 4; ++q) {
            part0[q] = fmaf(tanh_fast(acc0[nt][q]), w2v, part0[q]);
            part1[q] = fmaf(tanh_fast(acc1[nt][q]), w2v, part1[q]);
        }
    }
#pragma unroll
    for (int m = 1; m <= 8; m <<= 1) {
#pragma unroll
        for (int q = 0; q < 4; ++q) {
            part0[q] += __shfl_xor(part0[q], m, 64);
            part1[q] += __shfl_xor(part1[q], m, 64);
        }
    }
    if (r == 0) {
        const float bb2 = b2[0];
#pragma unroll
        for (int q = 0; q < 4; ++q) {
            att_exp[ebase + g * 4 + q]      = __expf(part0[q] + bb2);
            att_exp[ebase + 16 + g * 4 + q] = __expf(part1[q] + bb2);
        }
    }
}

// ---------------------------------------------------------------------------
// CSR build: histogram -> single-block scan (4 elems/thread) -> fill
// ---------------------------------------------------------------------------
__global__ __launch_bounds__(256) void k_hist(
    const int* __restrict__ srcI, int* __restrict__ cnt)
{
    const int e = blockIdx.x * 256 + threadIdx.x;
    atomicAdd(&cnt[srcI[e]], 1);
}

__global__ __launch_bounds__(1024) void k_scan(
    const int* __restrict__ cnt, int* __restrict__ rowptr)
{
    __shared__ int wsum[16];
    __shared__ int carry;
    const int tid = threadIdx.x, lane = tid & 63, wid = tid >> 6;
    if (tid == 0) { carry = 0; rowptr[0] = 0; }
    __syncthreads();
    for (int base = 0; base < N_NODES; base += 4096) {
        const int i = base + tid * 4;
        int4 c = {0, 0, 0, 0};
        if (i < N_NODES) c = *reinterpret_cast<const int4*>(cnt + i);
        const int tsum = c.x + c.y + c.z + c.w;
        int v = tsum;
#pragma unroll
        for (int d = 1; d < 64; d <<= 1) {
            const int t = __shfl_up(v, d, 64);
            if (lane >= d) v += t;
        }
        if (lane == 63) wsum[wid] = v;
        __syncthreads();
        if (wid == 0 && lane < 16) {
            int w = wsum[lane];
#pragma unroll
            for (int d = 1; d < 16; d <<= 1) {
                const int t = __shfl_up(w, d, 16);
                if ((lane & 15) >= d) w += t;
            }
            wsum[lane] = w;
        }
        __syncthreads();
        const int off = (wid == 0) ? 0 : wsum[wid - 1];
        const int excl = carry + off + v - tsum;   // exclusive start for this thread
        if (i < N_NODES) {
            rowptr[i + 1] = excl + c.x;
            rowptr[i + 2] = excl + c.x + c.y;
            rowptr[i + 3] = excl + c.x + c.y + c.z;
            rowptr[i + 4] = excl + tsum;
        }
        const int total = wsum[15];
        __syncthreads();
        if (tid == 0) carry += total;
        __syncthreads();
    }
}

__global__ __launch_bounds__(256) void k_fill(
    const int* __restrict__ srcI, const int* __restrict__ dstI,
    const float* __restrict__ att_exp, const int* __restrict__ rowptr,
    int* __restrict__ cursor, float* __restrict__ csr_p, int* __restrict__ csr_d)
{
    const int e = blockIdx.x * 256 + threadIdx.x;
    const int s = srcI[e];
    const int pos = rowptr[s] + atomicAdd(&cursor[s], 1);
    csr_p[pos] = att_exp[e];
    csr_d[pos] = dstI[e];
}

// ---------------------------------------------------------------------------
// K3: per-node gather-aggregate: agg[n] = sum(p*h[dst]) / sum(p)
// ---------------------------------------------------------------------------
__global__ __launch_bounds__(256) void k_agg(
    const int* __restrict__ rowptr, const float* __restrict__ csr_p,
    const int* __restrict__ csr_d, const ushort* __restrict__ Hb,
    float* __restrict__ agg)
{
    __shared__ float4 red[8][32];
    __shared__ float sred[8];
    const int tid = threadIdx.x, tc = tid & 31, slot = tid >> 5;
    const int n = blockIdx.x;
    const int beg = rowptr[n], end = rowptr[n + 1];

    float4 v = {0.f, 0.f, 0.f, 0.f};
    float sp = 0.f;
    for (int j = beg + slot; j < end; j += 8) {
        const float p = csr_p[j];
        const int d = csr_d[j];
        const ushort4 hv = *reinterpret_cast<const ushort4*>(Hb + (size_t)d * 128 + tc * 4);
        v.x = fmaf(p, bf2f(hv.x), v.x);
        v.y = fmaf(p, bf2f(hv.y), v.y);
        v.z = fmaf(p, bf2f(hv.z), v.z);
        v.w = fmaf(p, bf2f(hv.w), v.w);
        sp += p;
    }
    red[slot][tc] = v;
    if (tc == 0) sred[slot] = sp;
    __syncthreads();
    if (tid < 32) {
        float4 a = red[0][tid];
        float S = sred[0];
#pragma unroll
        for (int s = 1; s < 8; ++s) {
            const float4 b = red[s][tid];
            a.x += b.x; a.y += b.y; a.z += b.z; a.w += b.w;
            S += sred[s];
        }
        const float inv = (end > beg) ? 1.f / S : 0.f;
        const float4 o = {a.x * inv, a.y * inv, a.z * inv, a.w * inv};
        reinterpret_cast<float4*>(agg)[(size_t)n * 32 + tid] = o;
    }
}

// ---------------------------------------------------------------------------
// K4: o = agg @ W_out + b_out ; LayerNorm ; ReLU
// ---------------------------------------------------------------------------
__global__ __launch_bounds__(512) void k_out_ln(
    const float* __restrict__ AGG, const float* __restrict__ W,
    const float* __restrict__ b, const float* __restrict__ gamma,
    const float* __restrict__ beta, float* __restrict__ OUT)
{
    __shared__ float xs[4 * 128];
    __shared__ float red[8][2];
    const int tid = threadIdx.x;
    const int col = tid & 127, g = tid >> 7;
    const int node = blockIdx.x * 4 + g;

    xs[tid] = AGG[(size_t)node * 128 + col];
    __syncthreads();

    float acc = b[col];
    for (int k = 0; k < 128; ++k)
        acc = fmaf(xs[g * 128 + k], W[k * 128 + col], acc);

    float s1 = acc, s2 = acc * acc;
#pragma unroll
    for (int m = 1; m < 64; m <<= 1) {
        s1 += __shfl_xor(s1, m, 64);
        s2 += __shfl_xor(s2, m, 64);
    }
    const int wid = tid >> 6;
    if ((tid & 63) == 0) { red[wid][0] = s1; red[wid][1] = s2; }
    __syncthreads();

    const float S1 = red[2 * g][0] + red[2 * g + 1][0];
    const float S2 = red[2 * g][1] + red[2 * g + 1][1];
    const float mu = S1 * (1.f / 128.f);
    const float var = S2 * (1.f / 128.f) - mu * mu;
    const float rr = rsqrtf(var + 1e-5f);
    const float o = (acc - mu) * rr * gamma[col] + beta[col];
    OUT[(size_t)node * 128 + col] = o > 0.f ? o : 0.f;
}

// ---------------------------------------------------------------------------
extern "C" void kernel_launch(void* const* d_in, const int* in_sizes, int n_in,
                              void* d_out, int out_size, void* d_ws, size_t ws_size,
                              hipStream_t stream)
{
    const float* node_features = (const float*)d_in[0];
    const int*   edge_index    = (const int*)d_in[1];
    const float* edge_features = (const float*)d_in[2];
    const float* W_node  = (const float*)d_in[3];
    const float* b_node  = (const float*)d_in[4];
    const float* W_edge  = (const float*)d_in[5];
    const float* b_edge  = (const float*)d_in[6];
    const float* W_att1  = (const float*)d_in[7];
    const float* b_att1  = (const float*)d_in[8];
    const float* W_att2  = (const float*)d_in[9];
    const float* b_att2  = (const float*)d_in[10];
    const float* W_out   = (const float*)d_in[11];
    const float* b_out   = (const float*)d_in[12];
    const float* ln_gamma = (const float*)d_in[13];
    const float* ln_beta  = (const float*)d_in[14];
    float* out = (float*)d_out;

    // workspace layout (byte offsets, 16B-aligned)
    char* ws = (char*)d_ws;
    ushort* hb      = (ushort*)(ws);                   // 10,240,000 B
    float*  att_exp = (float*)(ws + 10240000);         //  2,560,000 B
    float*  csr_p   = (float*)(ws + 12800000);         //  2,560,000 B
    int*    csr_d   = (int*)(ws + 15360000);           //  2,560,000 B
    int*    rowptr  = (int*)(ws + 17920000);           //    160,004 B
    int*    cnt     = (int*)(ws + 18080016);           //    160,000 B
    int*    cursor  = (int*)(ws + 18240016);           //    160,000 B (contiguous after cnt)
    float*  agg     = (float*)(ws + 18400016);         // 20,480,000 B
    float*  Wc      = (float*)(ws + 38880016);         //     32,768 B
    float*  b_eff   = (float*)(ws + 38912784);         //        512 B
    ushort* pack    = (ushort*)(ws + 38913296);        //     81,920 B

    const int* srcI = edge_index;
    const int* dstI = edge_index + N_EDGES;

    // zero histogram + fill cursors (contiguous)
    hipMemsetAsync(cnt, 0, 320000, stream);

    k_node_gemm<<<N_NODES / 16, 256, 0, stream>>>(node_features, W_node, b_node, hb);
    k_wcomb<<<33, 256, 0, stream>>>(W_edge, W_att1, b_att1, b_edge, Wc, b_eff);
    k_pack<<<160, 256, 0, stream>>>(W_att1, Wc, pack);
    k_hist<<<N_EDGES / 256, 256, 0, stream>>>(srcI, cnt);
    k_scan<<<1, 1024, 0, stream>>>(cnt, rowptr);
    k_edge_att_mfma<<<N_EDGES / 256, 512, 0, stream>>>(srcI, dstI, edge_features, hb,
                                                       pack, b_eff, W_att2, b_att2,
                                                       att_exp);
    k_fill<<<N_EDGES / 256, 256, 0, stream>>>(srcI, dstI, att_exp, rowptr,
                                              cursor, csr_p, csr_d);
    k_agg<<<N_NODES, 256, 0, stream>>>(rowptr, csr_p, csr_d, hb, agg);
    k_out_ln<<<N_NODES / 4, 512, 0, stream>>>(agg, W_out, b_out, ln_gamma, ln_beta, out);
}

// Round 12
// 371.524 us; speedup vs baseline: 6.2862x; 1.0166x over previous
//
#include <hip/hip_runtime.h>
#include <math.h>

#define N_NODES 40000
#define N_EDGES 640000
#define IN_DIM 128
#define EDGE_DIM 64
#define HID 128

typedef __attribute__((ext_vector_type(8))) short bf16x8;
typedef __attribute__((ext_vector_type(4))) float f32x4;

__device__ __forceinline__ ushort f2bf(float f) {
    unsigned int x = __float_as_uint(f);
    x += 0x7fffu + ((x >> 16) & 1u);
    return (ushort)(x >> 16);
}
__device__ __forceinline__ float bf2f(ushort u) {
    return __uint_as_float(((unsigned int)u) << 16);
}
// tanh(x) = 1 - 2/(e^{2x}+1); e^{2x}=inf -> 1, e^{2x}=0 -> -1 (no NaN)
__device__ __forceinline__ float tanh_fast(float x) {
    return 1.f - __fdividef(2.f, __expf(2.f * x) + 1.f);
}

// ---------------------------------------------------------------------------
// K1: h = node_features @ W_node + b_node ; bf16 output only.
// ---------------------------------------------------------------------------
__global__ __launch_bounds__(256) void k_node_gemm(
    const float* __restrict__ X, const float* __restrict__ W,
    const float* __restrict__ b, ushort* __restrict__ Hb)
{
    __shared__ float xs[16 * 128];
    const int tid = threadIdx.x;
    const int base = blockIdx.x * 16;

    const float4* Xg = reinterpret_cast<const float4*>(X + (size_t)base * 128);
    float4* xs4 = reinterpret_cast<float4*>(xs);
#pragma unroll
    for (int i = 0; i < 2; ++i) xs4[tid + 256 * i] = Xg[tid + 256 * i];
    __syncthreads();

    const int col = tid & 127, g = tid >> 7;
    float acc[8];
#pragma unroll
    for (int i = 0; i < 8; ++i) acc[i] = 0.f;

    for (int k = 0; k < 128; ++k) {
        const float w = W[k * 128 + col];
#pragma unroll
        for (int i = 0; i < 8; ++i) acc[i] = fmaf(xs[(g + 2 * i) * 128 + k], w, acc[i]);
    }
    const float bb = b[col];
#pragma unroll
    for (int i = 0; i < 8; ++i)
        Hb[(size_t)(base + g + 2 * i) * 128 + col] = f2bf(acc[i] + bb);
}

// ---------------------------------------------------------------------------
// Setup A: W_comb = W_edge @ W1[256:384]; b_eff = b_att1 + b_edge @ W1he
// ---------------------------------------------------------------------------
__global__ __launch_bounds__(256) void k_wcomb(
    const float* __restrict__ W_edge, const float* __restrict__ W1,
    const float* __restrict__ b_att1, const float* __restrict__ b_edge,
    float* __restrict__ Wc, float* __restrict__ b_eff)
{
    const float* W1he = W1 + 256 * 128;
    if (blockIdx.x == 32) {
        const int n = threadIdx.x;
        if (n < 128) {
            float s = b_att1[n];
            for (int k = 0; k < 128; ++k) s = fmaf(b_edge[k], W1he[k * 128 + n], s);
            b_eff[n] = s;
        }
        return;
    }
    const int idx = blockIdx.x * 256 + threadIdx.x;
    const int row = idx >> 7, n = idx & 127;
    float s = 0.f;
    for (int k = 0; k < 128; ++k) s = fmaf(W_edge[row * 128 + k], W1he[k * 128 + n], s);
    Wc[idx] = s;
}

// ---------------------------------------------------------------------------
// Setup B: pack fragments, bf16.
//   idx <  32768 : packB (B-operand) for W1 rows 0..255 (G1/G2 GEMMs):
//                  k = k0*32+(lane>>4)*8+j, n = nt*16+(lane&15)
//   idx >= 32768 : packA (A-operand) for Wc^T (edge GEMM):
//                  A[row=16mt+r][k=32k0+8g+j] = Wc[k][row]
// ---------------------------------------------------------------------------
__global__ __launch_bounds__(256) void k_pack(
    const float* __restrict__ W1, const float* __restrict__ Wc,
    ushort* __restrict__ packB, ushort* __restrict__ packA)
{
    const int idx = blockIdx.x * 256 + threadIdx.x;   // 0..40959
    if (idx < 32768) {
        const int j = idx & 7, lane = (idx >> 3) & 63, nt = (idx >> 9) & 7, k0 = idx >> 12;
        const int k = k0 * 32 + (lane >> 4) * 8 + j;
        const int n = nt * 16 + (lane & 15);
        packB[idx] = f2bf(W1[k * 128 + n]);
    } else {
        const int i2 = idx - 32768;                   // 0..8191
        const int j = i2 & 7, lane = (i2 >> 3) & 63, mt = (i2 >> 9) & 7, k0 = i2 >> 12;
        const int r = lane & 15, g = lane >> 4;
        const int k = k0 * 32 + g * 8 + j;
        const int row = mt * 16 + r;
        packA[i2] = f2bf(Wc[k * 128 + row]);
    }
}

// ---------------------------------------------------------------------------
// K1b: G1 = Hb @ W1a + b_eff ; G2 = Hb @ W1b   (both [N,128] bf16)
// block 256 = 4 waves x 16 nodes.
// ---------------------------------------------------------------------------
__global__ __launch_bounds__(256) void k_node_g12(
    const ushort* __restrict__ Hb, const ushort* __restrict__ packB,
    const float* __restrict__ b_eff,
    ushort* __restrict__ G1, ushort* __restrict__ G2)
{
    const int tid = threadIdx.x;
    const int wave = tid >> 6, lane = tid & 63;
    const int r = lane & 15, g = lane >> 4;
    const int nbase = blockIdx.x * 64 + wave * 16;
    const ushort* rowA = Hb + (size_t)(nbase + r) * 128 + g * 8;
    const bf16x8* Bp = reinterpret_cast<const bf16x8*>(packB);

    f32x4 acc[8];
#pragma unroll
    for (int nt = 0; nt < 8; ++nt) acc[nt] = (f32x4){0.f, 0.f, 0.f, 0.f};
#pragma unroll
    for (int k0 = 0; k0 < 4; ++k0) {
        const bf16x8 a = *reinterpret_cast<const bf16x8*>(rowA + k0 * 32);
#pragma unroll
        for (int nt = 0; nt < 8; ++nt)
            acc[nt] = __builtin_amdgcn_mfma_f32_16x16x32_bf16(
                a, Bp[(k0 * 8 + nt) * 64 + lane], acc[nt], 0, 0, 0);
    }
#pragma unroll
    for (int nt = 0; nt < 8; ++nt) {
        const float bv = b_eff[nt * 16 + r];
#pragma unroll
        for (int q = 0; q < 4; ++q)
            G1[(size_t)(nbase + g * 4 + q) * 128 + nt * 16 + r] = f2bf(acc[nt][q] + bv);
    }

#pragma unroll
    for (int nt = 0; nt < 8; ++nt) acc[nt] = (f32x4){0.f, 0.f, 0.f, 0.f};
#pragma unroll
    for (int k0 = 0; k0 < 4; ++k0) {
        const bf16x8 a = *reinterpret_cast<const bf16x8*>(rowA + k0 * 32);
#pragma unroll
        for (int nt = 0; nt < 8; ++nt)
            acc[nt] = __builtin_amdgcn_mfma_f32_16x16x32_bf16(
                a, Bp[((k0 + 4) * 8 + nt) * 64 + lane], acc[nt], 0, 0, 0);
    }
#pragma unroll
    for (int nt = 0; nt < 8; ++nt) {
#pragma unroll
        for (int q = 0; q < 4; ++q)
            G2[(size_t)(nbase + g * 4 + q) * 128 + nt * 16 + r] = f2bf(acc[nt][q]);
    }
}

// ---------------------------------------------------------------------------
// K2 v3: z^T = Wc^T @ EF^T (MFMA, A from 16KB LDS), += G1[src] + G2[dst]
// (per-lane ushort4 gathers in accumulator layout), tanh, dot W2, exp.
// 512 thr = 8 waves x 16 edges. Lane (r,g) owns z cols {16mt+4g+q} of edge r.
// ---------------------------------------------------------------------------
__global__ __launch_bounds__(512) void k_edge_att_v3(
    const int* __restrict__ srcI, const int* __restrict__ dstI,
    const float* __restrict__ EF,
    const ushort* __restrict__ G1, const ushort* __restrict__ G2,
    const ushort* __restrict__ packA,
    const float* __restrict__ W2, const float* __restrict__ b2,
    float* __restrict__ att_exp)
{
    __shared__ ushort ash[8192];   // 16 KB: packA (Wc^T fragments)
    const int tid = threadIdx.x;
    {
        const bf16x8* Ag = reinterpret_cast<const bf16x8*>(packA);
        bf16x8* As = reinterpret_cast<bf16x8*>(ash);
        As[tid] = Ag[tid];
        As[tid + 512] = Ag[tid + 512];
    }
    __syncthreads();
    const bf16x8* Ap = reinterpret_cast<const bf16x8*>(ash);

    const int wave = tid >> 6, lane = tid & 63;
    const int r = lane & 15, g = lane >> 4;
    const int ebase = blockIdx.x * 128 + wave * 16;
    const int e = ebase + r;
    const int si = srcI[e], di = dstI[e];

    // B-frags: EF[e][32*k0 + 8g + j], fp32 -> bf16
    const float* rowE = EF + (size_t)e * 64 + g * 8;
    bf16x8 b0, b1;
    {
        const float4 u0 = *reinterpret_cast<const float4*>(rowE);
        const float4 u1 = *reinterpret_cast<const float4*>(rowE + 4);
        b0[0] = (short)f2bf(u0.x); b0[1] = (short)f2bf(u0.y);
        b0[2] = (short)f2bf(u0.z); b0[3] = (short)f2bf(u0.w);
        b0[4] = (short)f2bf(u1.x); b0[5] = (short)f2bf(u1.y);
        b0[6] = (short)f2bf(u1.z); b0[7] = (short)f2bf(u1.w);
        const float4 v0 = *reinterpret_cast<const float4*>(rowE + 32);
        const float4 v1 = *reinterpret_cast<const float4*>(rowE + 36);
        b1[0] = (short)f2bf(v0.x); b1[1] = (short)f2bf(v0.y);
        b1[2] = (short)f2bf(v0.z); b1[3] = (short)f2bf(v0.w);
        b1[4] = (short)f2bf(v1.x); b1[5] = (short)f2bf(v1.y);
        b1[6] = (short)f2bf(v1.z); b1[7] = (short)f2bf(v1.w);
    }

    f32x4 acc[8];
#pragma unroll
    for (int mt = 0; mt < 8; ++mt) acc[mt] = (f32x4){0.f, 0.f, 0.f, 0.f};
#pragma unroll
    for (int mt = 0; mt < 8; ++mt)
        acc[mt] = __builtin_amdgcn_mfma_f32_16x16x32_bf16(
            Ap[(0 * 8 + mt) * 64 + lane], b0, acc[mt], 0, 0, 0);
#pragma unroll
    for (int mt = 0; mt < 8; ++mt)
        acc[mt] = __builtin_amdgcn_mfma_f32_16x16x32_bf16(
            Ap[(1 * 8 + mt) * 64 + lane], b1, acc[mt], 0, 0, 0);

    // z += G1[src] + G2[dst] ; a = sum tanh(z)*W2
    const ushort* g1row = G1 + (size_t)si * 128 + g * 4;
    const ushort* g2row = G2 + (size_t)di * 128 + g * 4;
    float part = 0.f;
#pragma unroll
    for (int mt = 0; mt < 8; ++mt) {
        const int c0 = mt * 16;
        const ushort4 g1v = *reinterpret_cast<const ushort4*>(g1row + c0);
        const ushort4 g2v = *reinterpret_cast<const ushort4*>(g2row + c0);
        const float4 w2v = *reinterpret_cast<const float4*>(W2 + c0 + g * 4);
        const float z0 = acc[mt][0] + bf2f(g1v.x) + bf2f(g2v.x);
        const float z1 = acc[mt][1] + bf2f(g1v.y) + bf2f(g2v.y);
        const float z2 = acc[mt][2] + bf2f(g1v.z) + bf2f(g2v.z);
        const float z3 = acc[mt][3] + bf2f(g1v.w) + bf2f(g2v.w);
        part = fmaf(tanh_fast(z0), w2v.x, part);
        part = fmaf(tanh_fast(z1), w2v.y, part);
        part = fmaf(tanh_fast(z2), w2v.z, part);
        part = fmaf(tanh_fast(z3), w2v.w, part);
    }
    part += __shfl_xor(part, 16, 64);
    part += __shfl_xor(part, 32, 64);
    if (lane < 16) att_exp[ebase + lane] = __expf(part + b2[0]);
}

// ---------------------------------------------------------------------------
// CSR build: histogram -> single-block scan (4 elems/thread) -> fill
// ---------------------------------------------------------------------------
__global__ __launch_bounds__(256) void k_hist(
    const int* __restrict__ srcI, int* __restrict__ cnt)
{
    const int e = blockIdx.x * 256 + threadIdx.x;
    atomicAdd(&cnt[srcI[e]], 1);
}

__global__ __launch_bounds__(1024) void k_scan(
    const int* __restrict__ cnt, int* __restrict__ rowptr)
{
    __shared__ int wsum[16];
    __shared__ int carry;
    const int tid = threadIdx.x, lane = tid & 63, wid = tid >> 6;
    if (tid == 0) { carry = 0; rowptr[0] = 0; }
    __syncthreads();
    for (int base = 0; base < N_NODES; base += 4096) {
        const int i = base + tid * 4;
        int4 c = {0, 0, 0, 0};
        if (i < N_NODES) c = *reinterpret_cast<const int4*>(cnt + i);
        const int tsum = c.x + c.y + c.z + c.w;
        int v = tsum;
#pragma unroll
        for (int d = 1; d < 64; d <<= 1) {
            const int t = __shfl_up(v, d, 64);
            if (lane >= d) v += t;
        }
        if (lane == 63) wsum[wid] = v;
        __syncthreads();
        if (wid == 0 && lane < 16) {
            int w = wsum[lane];
#pragma unroll
            for (int d = 1; d < 16; d <<= 1) {
                const int t = __shfl_up(w, d, 16);
                if ((lane & 15) >= d) w += t;
            }
            wsum[lane] = w;
        }
        __syncthreads();
        const int off = (wid == 0) ? 0 : wsum[wid - 1];
        const int excl = carry + off + v - tsum;
        if (i < N_NODES) {
            rowptr[i + 1] = excl + c.x;
            rowptr[i + 2] = excl + c.x + c.y;
            rowptr[i + 3] = excl + c.x + c.y + c.z;
            rowptr[i + 4] = excl + tsum;
        }
        const int total = wsum[15];
        __syncthreads();
        if (tid == 0) carry += total;
        __syncthreads();
    }
}

__global__ __launch_bounds__(256) void k_fill(
    const int* __restrict__ srcI, const int* __restrict__ dstI,
    const float* __restrict__ att_exp, const int* __restrict__ rowptr,
    int* __restrict__ cursor, float* __restrict__ csr_p, int* __restrict__ csr_d)
{
    const int e = blockIdx.x * 256 + threadIdx.x;
    const int s = srcI[e];
    const int pos = rowptr[s] + atomicAdd(&cursor[s], 1);
    csr_p[pos] = att_exp[e];
    csr_d[pos] = dstI[e];
}

// ---------------------------------------------------------------------------
// K3: per-node gather-aggregate, wave-per-node (no LDS, no __syncthreads).
// 256 thr = 4 waves = 4 nodes; lane = (slot: 2 edges/iter) x (tc: 4 cols).
// ---------------------------------------------------------------------------
__global__ __launch_bounds__(256) void k_agg(
    const int* __restrict__ rowptr, const float* __restrict__ csr_p,
    const int* __restrict__ csr_d, const ushort* __restrict__ Hb,
    float* __restrict__ agg)
{
    const int tid = threadIdx.x;
    const int wave = tid >> 6, lane = tid & 63;
    const int slot = lane >> 5, tc = lane & 31;
    const int n = blockIdx.x * 4 + wave;
    const int beg = rowptr[n], end = rowptr[n + 1];

    float4 v = {0.f, 0.f, 0.f, 0.f};
    float sp = 0.f;
    for (int j = beg + slot; j < end; j += 2) {
        const float p = csr_p[j];
        const int d = csr_d[j];
        const ushort4 hv = *reinterpret_cast<const ushort4*>(Hb + (size_t)d * 128 + tc * 4);
        v.x = fmaf(p, bf2f(hv.x), v.x);
        v.y = fmaf(p, bf2f(hv.y), v.y);
        v.z = fmaf(p, bf2f(hv.z), v.z);
        v.w = fmaf(p, bf2f(hv.w), v.w);
        sp += p;
    }
    v.x += __shfl_xor(v.x, 32, 64);
    v.y += __shfl_xor(v.y, 32, 64);
    v.z += __shfl_xor(v.z, 32, 64);
    v.w += __shfl_xor(v.w, 32, 64);
    sp  += __shfl_xor(sp, 32, 64);
    if (lane < 32) {
        const float inv = (end > beg) ? 1.f / sp : 0.f;
        const float4 o = {v.x * inv, v.y * inv, v.z * inv, v.w * inv};
        reinterpret_cast<float4*>(agg)[(size_t)n * 32 + lane] = o;
    }
}

// ---------------------------------------------------------------------------
// K4: o = agg @ W_out + b_out ; LayerNorm ; ReLU
// ---------------------------------------------------------------------------
__global__ __launch_bounds__(512) void k_out_ln(
    const float* __restrict__ AGG, const float* __restrict__ W,
    const float* __restrict__ b, const float* __restrict__ gamma,
    const float* __restrict__ beta, float* __restrict__ OUT)
{
    __shared__ float xs[4 * 128];
    __shared__ float red[8][2];
    const int tid = threadIdx.x;
    const int col = tid & 127, g = tid >> 7;
    const int node = blockIdx.x * 4 + g;

    xs[tid] = AGG[(size_t)node * 128 + col];
    __syncthreads();

    float acc = b[col];
    for (int k = 0; k < 128; ++k)
        acc = fmaf(xs[g * 128 + k], W[k * 128 + col], acc);

    float s1 = acc, s2 = acc * acc;
#pragma unroll
    for (int m = 1; m < 64; m <<= 1) {
        s1 += __shfl_xor(s1, m, 64);
        s2 += __shfl_xor(s2, m, 64);
    }
    const int wid = tid >> 6;
    if ((tid & 63) == 0) { red[wid][0] = s1; red[wid][1] = s2; }
    __syncthreads();

    const float S1 = red[2 * g][0] + red[2 * g + 1][0];
    const float S2 = red[2 * g][1] + red[2 * g + 1][1];
    const float mu = S1 * (1.f / 128.f);
    const float var = S2 * (1.f / 128.f) - mu * mu;
    const float rr = rsqrtf(var + 1e-5f);
    const float o = (acc - mu) * rr * gamma[col] + beta[col];
    OUT[(size_t)node * 128 + col] = o > 0.f ? o : 0.f;
}

// ---------------------------------------------------------------------------
extern "C" void kernel_launch(void* const* d_in, const int* in_sizes, int n_in,
                              void* d_out, int out_size, void* d_ws, size_t ws_size,
                              hipStream_t stream)
{
    const float* node_features = (const float*)d_in[0];
    const int*   edge_index    = (const int*)d_in[1];
    const float* edge_features = (const float*)d_in[2];
    const float* W_node  = (const float*)d_in[3];
    const float* b_node  = (const float*)d_in[4];
    const float* W_edge  = (const float*)d_in[5];
    const float* b_edge  = (const float*)d_in[6];
    const float* W_att1  = (const float*)d_in[7];
    const float* b_att1  = (const float*)d_in[8];
    const float* W_att2  = (const float*)d_in[9];
    const float* b_att2  = (const float*)d_in[10];
    const float* W_out   = (const float*)d_in[11];
    const float* b_out   = (const float*)d_in[12];
    const float* ln_gamma = (const float*)d_in[13];
    const float* ln_beta  = (const float*)d_in[14];
    float* out = (float*)d_out;

    // workspace layout (byte offsets, 16B-aligned). agg aliases G1+G2 (dead
    // after k_edge_att_v3; k_agg reads only Hb/csr/rowptr, all disjoint).
    char* ws = (char*)d_ws;
    ushort* hb      = (ushort*)(ws);                   // 10,240,000 B
    ushort* G1      = (ushort*)(ws + 10240000);        // 10,240,000 B
    ushort* G2      = (ushort*)(ws + 20480000);        // 10,240,000 B
    float*  agg     = (float*)(ws + 10240000);         // 20,480,000 B (alias G1+G2)
    float*  att_exp = (float*)(ws + 30720000);         //  2,560,000 B
    float*  csr_p   = (float*)(ws + 33280000);         //  2,560,000 B
    int*    csr_d   = (int*)(ws + 35840000);           //  2,560,000 B
    int*    rowptr  = (int*)(ws + 38400000);           //    160,004 B
    int*    cnt     = (int*)(ws + 38560016);           //    160,000 B
    int*    cursor  = (int*)(ws + 38720016);           //    160,000 B (contiguous after cnt)
    float*  Wc      = (float*)(ws + 38880016);         //     32,768 B
    float*  b_eff   = (float*)(ws + 38912784);         //        512 B
    ushort* packB   = (ushort*)(ws + 38913296);        //     65,536 B
    ushort* packA   = (ushort*)(ws + 38978832);        //     16,384 B

    const int* srcI = edge_index;
    const int* dstI = edge_index + N_EDGES;

    // zero histogram + fill cursors (contiguous)
    hipMemsetAsync(cnt, 0, 320000, stream);

    k_node_gemm<<<N_NODES / 16, 256, 0, stream>>>(node_features, W_node, b_node, hb);
    k_wcomb<<<33, 256, 0, stream>>>(W_edge, W_att1, b_att1, b_edge, Wc, b_eff);
    k_pack<<<160, 256, 0, stream>>>(W_att1, Wc, packB, packA);
    k_node_g12<<<N_NODES / 64, 256, 0, stream>>>(hb, packB, b_eff, G1, G2);
    k_hist<<<N_EDGES / 256, 256, 0, stream>>>(srcI, cnt);
    k_scan<<<1, 1024, 0, stream>>>(cnt, rowptr);
    k_edge_att_v3<<<N_EDGES / 128, 512, 0, stream>>>(srcI, dstI, edge_features,
                                                     G1, G2, packA, W_att2, b_att2,
                                                     att_exp);
    k_fill<<<N_EDGES / 256, 256, 0, stream>>>(srcI, dstI, att_exp, rowptr,
                                              cursor, csr_p, csr_d);
    k_agg<<<N_NODES / 4, 256, 0, stream>>>(rowptr, csr_p, csr_d, hb, agg);
    k_out_ln<<<N_NODES / 4, 512, 0, stream>>>(agg, W_out, b_out, ln_gamma, ln_beta, out);
}

// Round 13
// 267.638 us; speedup vs baseline: 8.7262x; 1.3882x over previous
//
#include <hip/hip_runtime.h>
#include <math.h>

#define N_NODES 40000
#define N_EDGES 640000
#define IN_DIM 128
#define EDGE_DIM 64
#define HID 128

typedef __attribute__((ext_vector_type(8))) short bf16x8;
typedef __attribute__((ext_vector_type(4))) float f32x4;

__device__ __forceinline__ ushort f2bf(float f) {
    unsigned int x = __float_as_uint(f);
    x += 0x7fffu + ((x >> 16) & 1u);
    return (ushort)(x >> 16);
}
__device__ __forceinline__ float bf2f(ushort u) {
    return __uint_as_float(((unsigned int)u) << 16);
}
// tanh(x) = 1 - 2/(e^{2x}+1); e^{2x}=inf -> 1, e^{2x}=0 -> -1 (no NaN)
__device__ __forceinline__ float tanh_fast(float x) {
    return 1.f - __fdividef(2.f, __expf(2.f * x) + 1.f);
}

// ---------------------------------------------------------------------------
// Setup A: W_comb = W_edge @ W1[256:384]; b_eff = b_att1 + b_edge @ W1he
// ---------------------------------------------------------------------------
__global__ __launch_bounds__(256) void k_wcomb(
    const float* __restrict__ W_edge, const float* __restrict__ W1,
    const float* __restrict__ b_att1, const float* __restrict__ b_edge,
    float* __restrict__ Wc, float* __restrict__ b_eff)
{
    const float* W1he = W1 + 256 * 128;
    if (blockIdx.x == 32) {
        const int n = threadIdx.x;
        if (n < 128) {
            float s = b_att1[n];
            for (int k = 0; k < 128; ++k) s = fmaf(b_edge[k], W1he[k * 128 + n], s);
            b_eff[n] = s;
        }
        return;
    }
    const int idx = blockIdx.x * 256 + threadIdx.x;
    const int row = idx >> 7, n = idx & 127;
    float s = 0.f;
    for (int k = 0; k < 128; ++k) s = fmaf(W_edge[row * 128 + k], W1he[k * 128 + n], s);
    Wc[idx] = s;
}

// ---------------------------------------------------------------------------
// Setup B: pack all weight fragments, bf16.
//  idx<32768          : packB  (B-op, W1 rows 0..255, G1/G2 GEMMs)
//  32768..40959       : packA  (A-op, Wc^T, edge GEMM)
//  40960..57343       : packN  (B-op, W_node)
//  57344..73727       : packO  (B-op, W_out)
// B-op: k=k0*32+(lane>>4)*8+j, n=nt*16+(lane&15). A-op: row=mt*16+r, k=k0*32+g*8+j.
// ---------------------------------------------------------------------------
__global__ __launch_bounds__(256) void k_pack(
    const float* __restrict__ W1, const float* __restrict__ Wc,
    const float* __restrict__ Wn, const float* __restrict__ Wo,
    ushort* __restrict__ packB, ushort* __restrict__ packA,
    ushort* __restrict__ packN, ushort* __restrict__ packO)
{
    const int idx = blockIdx.x * 256 + threadIdx.x;   // 0..73727
    if (idx < 32768) {
        const int j = idx & 7, lane = (idx >> 3) & 63, nt = (idx >> 9) & 7, k0 = idx >> 12;
        const int k = k0 * 32 + (lane >> 4) * 8 + j;
        const int n = nt * 16 + (lane & 15);
        packB[idx] = f2bf(W1[k * 128 + n]);
    } else if (idx < 40960) {
        const int i2 = idx - 32768;
        const int j = i2 & 7, lane = (i2 >> 3) & 63, mt = (i2 >> 9) & 7, k0 = i2 >> 12;
        const int k = k0 * 32 + (lane >> 4) * 8 + j;
        const int row = mt * 16 + (lane & 15);
        packA[i2] = f2bf(Wc[k * 128 + row]);
    } else if (idx < 57344) {
        const int i3 = idx - 40960;
        const int j = i3 & 7, lane = (i3 >> 3) & 63, nt = (i3 >> 9) & 7, k0 = i3 >> 12;
        const int k = k0 * 32 + (lane >> 4) * 8 + j;
        const int n = nt * 16 + (lane & 15);
        packN[i3] = f2bf(Wn[k * 128 + n]);
    } else {
        const int i4 = idx - 57344;
        const int j = i4 & 7, lane = (i4 >> 3) & 63, nt = (i4 >> 9) & 7, k0 = i4 >> 12;
        const int k = k0 * 32 + (lane >> 4) * 8 + j;
        const int n = nt * 16 + (lane & 15);
        packO[i4] = f2bf(Wo[k * 128 + n]);
    }
}

// ---------------------------------------------------------------------------
// K1: h = X @ W_node + b_node via MFMA (X fp32 -> bf16 on the fly); Hb bf16.
// 256 thr = 4 waves x 16 nodes.
// ---------------------------------------------------------------------------
__global__ __launch_bounds__(256) void k_node_gemm(
    const float* __restrict__ X, const ushort* __restrict__ packN,
    const float* __restrict__ b, ushort* __restrict__ Hb)
{
    const int tid = threadIdx.x;
    const int wave = tid >> 6, lane = tid & 63;
    const int r = lane & 15, g = lane >> 4;
    const int nbase = blockIdx.x * 64 + wave * 16;
    const float* rowX = X + (size_t)(nbase + r) * 128 + g * 8;
    const bf16x8* Bp = reinterpret_cast<const bf16x8*>(packN);

    f32x4 acc[8];
#pragma unroll
    for (int nt = 0; nt < 8; ++nt) {
        const float bv = b[nt * 16 + r];
        acc[nt] = (f32x4){bv, bv, bv, bv};
    }
#pragma unroll
    for (int k0 = 0; k0 < 4; ++k0) {
        const float4 u0 = *reinterpret_cast<const float4*>(rowX + k0 * 32);
        const float4 u1 = *reinterpret_cast<const float4*>(rowX + k0 * 32 + 4);
        bf16x8 a;
        a[0] = (short)f2bf(u0.x); a[1] = (short)f2bf(u0.y);
        a[2] = (short)f2bf(u0.z); a[3] = (short)f2bf(u0.w);
        a[4] = (short)f2bf(u1.x); a[5] = (short)f2bf(u1.y);
        a[6] = (short)f2bf(u1.z); a[7] = (short)f2bf(u1.w);
#pragma unroll
        for (int nt = 0; nt < 8; ++nt)
            acc[nt] = __builtin_amdgcn_mfma_f32_16x16x32_bf16(
                a, Bp[(k0 * 8 + nt) * 64 + lane], acc[nt], 0, 0, 0);
    }
#pragma unroll
    for (int nt = 0; nt < 8; ++nt) {
#pragma unroll
        for (int q = 0; q < 4; ++q)
            Hb[(size_t)(nbase + g * 4 + q) * 128 + nt * 16 + r] = f2bf(acc[nt][q]);
    }
}

// ---------------------------------------------------------------------------
// K1b: G1 = Hb @ W1a + b_eff ; G2 = Hb @ W1b   (both [N,128] bf16)
// ---------------------------------------------------------------------------
__global__ __launch_bounds__(256) void k_node_g12(
    const ushort* __restrict__ Hb, const ushort* __restrict__ packB,
    const float* __restrict__ b_eff,
    ushort* __restrict__ G1, ushort* __restrict__ G2)
{
    const int tid = threadIdx.x;
    const int wave = tid >> 6, lane = tid & 63;
    const int r = lane & 15, g = lane >> 4;
    const int nbase = blockIdx.x * 64 + wave * 16;
    const ushort* rowA = Hb + (size_t)(nbase + r) * 128 + g * 8;
    const bf16x8* Bp = reinterpret_cast<const bf16x8*>(packB);

    f32x4 acc[8];
#pragma unroll
    for (int nt = 0; nt < 8; ++nt) acc[nt] = (f32x4){0.f, 0.f, 0.f, 0.f};
#pragma unroll
    for (int k0 = 0; k0 < 4; ++k0) {
        const bf16x8 a = *reinterpret_cast<const bf16x8*>(rowA + k0 * 32);
#pragma unroll
        for (int nt = 0; nt < 8; ++nt)
            acc[nt] = __builtin_amdgcn_mfma_f32_16x16x32_bf16(
                a, Bp[(k0 * 8 + nt) * 64 + lane], acc[nt], 0, 0, 0);
    }
#pragma unroll
    for (int nt = 0; nt < 8; ++nt) {
        const float bv = b_eff[nt * 16 + r];
#pragma unroll
        for (int q = 0; q < 4; ++q)
            G1[(size_t)(nbase + g * 4 + q) * 128 + nt * 16 + r] = f2bf(acc[nt][q] + bv);
    }

#pragma unroll
    for (int nt = 0; nt < 8; ++nt) acc[nt] = (f32x4){0.f, 0.f, 0.f, 0.f};
#pragma unroll
    for (int k0 = 0; k0 < 4; ++k0) {
        const bf16x8 a = *reinterpret_cast<const bf16x8*>(rowA + k0 * 32);
#pragma unroll
        for (int nt = 0; nt < 8; ++nt)
            acc[nt] = __builtin_amdgcn_mfma_f32_16x16x32_bf16(
                a, Bp[((k0 + 4) * 8 + nt) * 64 + lane], acc[nt], 0, 0, 0);
    }
#pragma unroll
    for (int nt = 0; nt < 8; ++nt) {
#pragma unroll
        for (int q = 0; q < 4; ++q)
            G2[(size_t)(nbase + g * 4 + q) * 128 + nt * 16 + r] = f2bf(acc[nt][q]);
    }
}

// ---------------------------------------------------------------------------
// K2 v4: z^T = Wc^T @ EF^T (MFMA) + G1[src] + G2[dst]; tanh; dot W2; exp;
// fused CSR fill (p,dst) via cursor atomic. 256 thr = 4 waves x 16 edges.
// G gathers hoisted into registers BEFORE the MFMA block (latency overlap).
// ---------------------------------------------------------------------------
__global__ __launch_bounds__(256) void k_edge_att_v4(
    const int* __restrict__ srcI, const int* __restrict__ dstI,
    const float* __restrict__ EF,
    const ushort* __restrict__ G1, const ushort* __restrict__ G2,
    const ushort* __restrict__ packA,
    const float* __restrict__ W2, const float* __restrict__ b2,
    const int* __restrict__ rowptr, int* __restrict__ cursor,
    float* __restrict__ csr_p, int* __restrict__ csr_d)
{
    __shared__ ushort ash[8192];   // 16 KB: packA (Wc^T fragments)
    const int tid = threadIdx.x;
    {
        const bf16x8* Ag = reinterpret_cast<const bf16x8*>(packA);
        bf16x8* As = reinterpret_cast<bf16x8*>(ash);
        As[tid] = Ag[tid];
        As[tid + 256] = Ag[tid + 256];
        As[tid + 512] = Ag[tid + 512];
        As[tid + 768] = Ag[tid + 768];
    }
    __syncthreads();
    const bf16x8* Ap = reinterpret_cast<const bf16x8*>(ash);

    const int wave = tid >> 6, lane = tid & 63;
    const int r = lane & 15, g = lane >> 4;
    const int ebase = blockIdx.x * 64 + wave * 16;
    const int e = ebase + r;
    const int si = srcI[e], di = dstI[e];

    // hoisted gathers: G1[src], G2[dst] rows in accumulator layout
    const ushort* g1row = G1 + (size_t)si * 128 + g * 4;
    const ushort* g2row = G2 + (size_t)di * 128 + g * 4;
    ushort4 g1v[8], g2v[8];
#pragma unroll
    for (int mt = 0; mt < 8; ++mt) {
        g1v[mt] = *reinterpret_cast<const ushort4*>(g1row + mt * 16);
        g2v[mt] = *reinterpret_cast<const ushort4*>(g2row + mt * 16);
    }

    // B-frags: EF[e][32*k0 + 8g + j], fp32 -> bf16
    const float* rowE = EF + (size_t)e * 64 + g * 8;
    bf16x8 b0, b1;
    {
        const float4 u0 = *reinterpret_cast<const float4*>(rowE);
        const float4 u1 = *reinterpret_cast<const float4*>(rowE + 4);
        b0[0] = (short)f2bf(u0.x); b0[1] = (short)f2bf(u0.y);
        b0[2] = (short)f2bf(u0.z); b0[3] = (short)f2bf(u0.w);
        b0[4] = (short)f2bf(u1.x); b0[5] = (short)f2bf(u1.y);
        b0[6] = (short)f2bf(u1.z); b0[7] = (short)f2bf(u1.w);
        const float4 v0 = *reinterpret_cast<const float4*>(rowE + 32);
        const float4 v1 = *reinterpret_cast<const float4*>(rowE + 36);
        b1[0] = (short)f2bf(v0.x); b1[1] = (short)f2bf(v0.y);
        b1[2] = (short)f2bf(v0.z); b1[3] = (short)f2bf(v0.w);
        b1[4] = (short)f2bf(v1.x); b1[5] = (short)f2bf(v1.y);
        b1[6] = (short)f2bf(v1.z); b1[7] = (short)f2bf(v1.w);
    }

    f32x4 acc[8];
#pragma unroll
    for (int mt = 0; mt < 8; ++mt) acc[mt] = (f32x4){0.f, 0.f, 0.f, 0.f};
#pragma unroll
    for (int mt = 0; mt < 8; ++mt)
        acc[mt] = __builtin_amdgcn_mfma_f32_16x16x32_bf16(
            Ap[(0 * 8 + mt) * 64 + lane], b0, acc[mt], 0, 0, 0);
#pragma unroll
    for (int mt = 0; mt < 8; ++mt)
        acc[mt] = __builtin_amdgcn_mfma_f32_16x16x32_bf16(
            Ap[(1 * 8 + mt) * 64 + lane], b1, acc[mt], 0, 0, 0);

    // z += G1 + G2 ; a = sum tanh(z)*W2
    float part = 0.f;
#pragma unroll
    for (int mt = 0; mt < 8; ++mt) {
        const float4 w2v = *reinterpret_cast<const float4*>(W2 + mt * 16 + g * 4);
        const float z0 = acc[mt][0] + bf2f(g1v[mt].x) + bf2f(g2v[mt].x);
        const float z1 = acc[mt][1] + bf2f(g1v[mt].y) + bf2f(g2v[mt].y);
        const float z2 = acc[mt][2] + bf2f(g1v[mt].z) + bf2f(g2v[mt].z);
        const float z3 = acc[mt][3] + bf2f(g1v[mt].w) + bf2f(g2v[mt].w);
        part = fmaf(tanh_fast(z0), w2v.x, part);
        part = fmaf(tanh_fast(z1), w2v.y, part);
        part = fmaf(tanh_fast(z2), w2v.z, part);
        part = fmaf(tanh_fast(z3), w2v.w, part);
    }
    part += __shfl_xor(part, 16, 64);
    part += __shfl_xor(part, 32, 64);
    if (lane < 16) {
        const float p = __expf(part + b2[0]);
        const int pos = rowptr[si] + atomicAdd(&cursor[si], 1);
        csr_p[pos] = p;
        csr_d[pos] = di;
    }
}

// ---------------------------------------------------------------------------
// CSR build: histogram -> single-block scan (4 elems/thread)
// ---------------------------------------------------------------------------
__global__ __launch_bounds__(256) void k_hist(
    const int* __restrict__ srcI, int* __restrict__ cnt)
{
    const int e = blockIdx.x * 256 + threadIdx.x;
    atomicAdd(&cnt[srcI[e]], 1);
}

__global__ __launch_bounds__(1024) void k_scan(
    const int* __restrict__ cnt, int* __restrict__ rowptr)
{
    __shared__ int wsum[16];
    __shared__ int carry;
    const int tid = threadIdx.x, lane = tid & 63, wid = tid >> 6;
    if (tid == 0) { carry = 0; rowptr[0] = 0; }
    __syncthreads();
    for (int base = 0; base < N_NODES; base += 4096) {
        const int i = base + tid * 4;
        int4 c = {0, 0, 0, 0};
        if (i < N_NODES) c = *reinterpret_cast<const int4*>(cnt + i);
        const int tsum = c.x + c.y + c.z + c.w;
        int v = tsum;
#pragma unroll
        for (int d = 1; d < 64; d <<= 1) {
            const int t = __shfl_up(v, d, 64);
            if (lane >= d) v += t;
        }
        if (lane == 63) wsum[wid] = v;
        __syncthreads();
        if (wid == 0 && lane < 16) {
            int w = wsum[lane];
#pragma unroll
            for (int d = 1; d < 16; d <<= 1) {
                const int t = __shfl_up(w, d, 16);
                if ((lane & 15) >= d) w += t;
            }
            wsum[lane] = w;
        }
        __syncthreads();
        const int off = (wid == 0) ? 0 : wsum[wid - 1];
        const int excl = carry + off + v - tsum;
        if (i < N_NODES) {
            rowptr[i + 1] = excl + c.x;
            rowptr[i + 2] = excl + c.x + c.y;
            rowptr[i + 3] = excl + c.x + c.y + c.z;
            rowptr[i + 4] = excl + tsum;
        }
        const int total = wsum[15];
        __syncthreads();
        if (tid == 0) carry += total;
        __syncthreads();
    }
}

// ---------------------------------------------------------------------------
// K3: per-node gather-aggregate, wave-per-node; output bf16.
// ---------------------------------------------------------------------------
__global__ __launch_bounds__(256) void k_agg(
    const int* __restrict__ rowptr, const float* __restrict__ csr_p,
    const int* __restrict__ csr_d, const ushort* __restrict__ Hb,
    ushort* __restrict__ AGGb)
{
    const int tid = threadIdx.x;
    const int wave = tid >> 6, lane = tid & 63;
    const int slot = lane >> 5, tc = lane & 31;
    const int n = blockIdx.x * 4 + wave;
    const int beg = rowptr[n], end = rowptr[n + 1];

    float4 v = {0.f, 0.f, 0.f, 0.f};
    float sp = 0.f;
    for (int j = beg + slot; j < end; j += 2) {
        const float p = csr_p[j];
        const int d = csr_d[j];
        const ushort4 hv = *reinterpret_cast<const ushort4*>(Hb + (size_t)d * 128 + tc * 4);
        v.x = fmaf(p, bf2f(hv.x), v.x);
        v.y = fmaf(p, bf2f(hv.y), v.y);
        v.z = fmaf(p, bf2f(hv.z), v.z);
        v.w = fmaf(p, bf2f(hv.w), v.w);
        sp += p;
    }
    v.x += __shfl_xor(v.x, 32, 64);
    v.y += __shfl_xor(v.y, 32, 64);
    v.z += __shfl_xor(v.z, 32, 64);
    v.w += __shfl_xor(v.w, 32, 64);
    sp  += __shfl_xor(sp, 32, 64);
    if (lane < 32) {
        const float inv = (end > beg) ? 1.f / sp : 0.f;
        ushort4 o;
        o.x = f2bf(v.x * inv); o.y = f2bf(v.y * inv);
        o.z = f2bf(v.z * inv); o.w = f2bf(v.w * inv);
        *reinterpret_cast<ushort4*>(AGGb + (size_t)n * 128 + lane * 4) = o;
    }
}

// ---------------------------------------------------------------------------
// K4: o = agg @ W_out + b_out (MFMA) ; LayerNorm ; ReLU
// 256 thr = 4 waves x 16 nodes; LN reduced in C-fragment layout.
// ---------------------------------------------------------------------------
__global__ __launch_bounds__(256) void k_out_ln(
    const ushort* __restrict__ AGGb, const ushort* __restrict__ packO,
    const float* __restrict__ b, const float* __restrict__ gamma,
    const float* __restrict__ beta, float* __restrict__ OUT)
{
    const int tid = threadIdx.x;
    const int wave = tid >> 6, lane = tid & 63;
    const int r = lane & 15, g = lane >> 4;
    const int nbase = blockIdx.x * 64 + wave * 16;
    const ushort* rowA = AGGb + (size_t)(nbase + r) * 128 + g * 8;
    const bf16x8* Bp = reinterpret_cast<const bf16x8*>(packO);

    f32x4 acc[8];
#pragma unroll
    for (int nt = 0; nt < 8; ++nt) {
        const float bv = b[nt * 16 + r];
        acc[nt] = (f32x4){bv, bv, bv, bv};
    }
#pragma unroll
    for (int k0 = 0; k0 < 4; ++k0) {
        const bf16x8 a = *reinterpret_cast<const bf16x8*>(rowA + k0 * 32);
#pragma unroll
        for (int nt = 0; nt < 8; ++nt)
            acc[nt] = __builtin_amdgcn_mfma_f32_16x16x32_bf16(
                a, Bp[(k0 * 8 + nt) * 64 + lane], acc[nt], 0, 0, 0);
    }

    // LN over each row (g*4+q): reduce over nt in-lane, then over 16 r-lanes
    float s1[4] = {0.f, 0.f, 0.f, 0.f};
    float s2[4] = {0.f, 0.f, 0.f, 0.f};
#pragma unroll
    for (int nt = 0; nt < 8; ++nt) {
#pragma unroll
        for (int q = 0; q < 4; ++q) {
            const float z = acc[nt][q];
            s1[q] += z;
            s2[q] = fmaf(z, z, s2[q]);
        }
    }
#pragma unroll
    for (int m = 1; m <= 8; m <<= 1) {
#pragma unroll
        for (int q = 0; q < 4; ++q) {
            s1[q] += __shfl_xor(s1[q], m, 64);
            s2[q] += __shfl_xor(s2[q], m, 64);
        }
    }
    float mu[4], rr[4];
#pragma unroll
    for (int q = 0; q < 4; ++q) {
        mu[q] = s1[q] * (1.f / 128.f);
        const float var = s2[q] * (1.f / 128.f) - mu[q] * mu[q];
        rr[q] = rsqrtf(var + 1e-5f);
    }
#pragma unroll
    for (int nt = 0; nt < 8; ++nt) {
        const int col = nt * 16 + r;
        const float ga = gamma[col], be = beta[col];
#pragma unroll
        for (int q = 0; q < 4; ++q) {
            const float o = (acc[nt][q] - mu[q]) * rr[q] * ga + be;
            OUT[(size_t)(nbase + g * 4 + q) * 128 + col] = o > 0.f ? o : 0.f;
        }
    }
}

// ---------------------------------------------------------------------------
extern "C" void kernel_launch(void* const* d_in, const int* in_sizes, int n_in,
                              void* d_out, int out_size, void* d_ws, size_t ws_size,
                              hipStream_t stream)
{
    const float* node_features = (const float*)d_in[0];
    const int*   edge_index    = (const int*)d_in[1];
    const float* edge_features = (const float*)d_in[2];
    const float* W_node  = (const float*)d_in[3];
    const float* b_node  = (const float*)d_in[4];
    const float* W_edge  = (const float*)d_in[5];
    const float* b_edge  = (const float*)d_in[6];
    const float* W_att1  = (const float*)d_in[7];
    const float* b_att1  = (const float*)d_in[8];
    const float* W_att2  = (const float*)d_in[9];
    const float* b_att2  = (const float*)d_in[10];
    const float* W_out   = (const float*)d_in[11];
    const float* b_out   = (const float*)d_in[12];
    const float* ln_gamma = (const float*)d_in[13];
    const float* ln_beta  = (const float*)d_in[14];
    float* out = (float*)d_out;

    // workspace layout (byte offsets, 16B-aligned)
    char* ws = (char*)d_ws;
    ushort* hb      = (ushort*)(ws);                   // 10,240,000 B
    ushort* G1      = (ushort*)(ws + 10240000);        // 10,240,000 B
    ushort* G2      = (ushort*)(ws + 20480000);        // 10,240,000 B
    ushort* aggb    = (ushort*)(ws + 30720000);        // 10,240,000 B
    float*  csr_p   = (float*)(ws + 40960000);         //  2,560,000 B
    int*    csr_d   = (int*)(ws + 43520000);           //  2,560,000 B
    int*    rowptr  = (int*)(ws + 46080000);           //    160,004 B
    int*    cnt     = (int*)(ws + 46240016);           //    160,000 B
    int*    cursor  = (int*)(ws + 46400016);           //    160,000 B (contiguous after cnt)
    float*  Wc      = (float*)(ws + 46560016);         //     32,768 B
    float*  b_eff   = (float*)(ws + 46592784);         //        512 B
    ushort* packB   = (ushort*)(ws + 46593296);        //     65,536 B
    ushort* packA   = (ushort*)(ws + 46658832);        //     16,384 B
    ushort* packN   = (ushort*)(ws + 46675216);        //     32,768 B
    ushort* packO   = (ushort*)(ws + 46707984);        //     32,768 B

    const int* srcI = edge_index;
    const int* dstI = edge_index + N_EDGES;

    // zero histogram + fill cursors (contiguous)
    hipMemsetAsync(cnt, 0, 320000, stream);

    k_wcomb<<<33, 256, 0, stream>>>(W_edge, W_att1, b_att1, b_edge, Wc, b_eff);
    k_pack<<<288, 256, 0, stream>>>(W_att1, Wc, W_node, W_out,
                                    packB, packA, packN, packO);
    k_node_gemm<<<N_NODES / 64, 256, 0, stream>>>(node_features, packN, b_node, hb);
    k_node_g12<<<N_NODES / 64, 256, 0, stream>>>(hb, packB, b_eff, G1, G2);
    k_hist<<<N_EDGES / 256, 256, 0, stream>>>(srcI, cnt);
    k_scan<<<1, 1024, 0, stream>>>(cnt, rowptr);
    k_edge_att_v4<<<N_EDGES / 64, 256, 0, stream>>>(srcI, dstI, edge_features,
                                                    G1, G2, packA, W_att2, b_att2,
                                                    rowptr, cursor, csr_p, csr_d);
    k_agg<<<N_NODES / 4, 256, 0, stream>>>(rowptr, csr_p, csr_d, hb, aggb);
    k_out_ln<<<N_NODES / 64, 256, 0, stream>>>(aggb, packO, b_out, ln_gamma, ln_beta, out);
}